// Round 8
// baseline (202.707 us; speedup 1.0000x reference)
//
#include <hip/hip_runtime.h>
#include <hip/hip_bf16.h>
#include <math.h>

#define NH 12
#define DH 64
#define BB 2
#define NN 2048
#define DM 768

typedef short v8s __attribute__((ext_vector_type(8)));
typedef float v4f __attribute__((ext_vector_type(4)));
typedef float v16f __attribute__((ext_vector_type(16)));

__device__ __forceinline__ unsigned short f2bf(float f) {
    union { float f; unsigned u; } x; x.f = f;
    unsigned r = x.u + 0x7fffu + ((x.u >> 16) & 1u);
    return (unsigned short)(r >> 16);
}

__device__ __forceinline__ int cvtpk(float lo, float hi2) {
    int r;
    asm("v_cvt_pk_bf16_f32 %0, %1, %2" : "=v"(r) : "v"(lo), "v"(hi2));
    return r;
}

__device__ __forceinline__ void glds16(const void* g, void* l) {
    __builtin_amdgcn_global_load_lds((const __attribute__((address_space(1))) void*)g,
                                     (__attribute__((address_space(3))) void*)l, 16, 0, 0);
}

// ---- cast x (fp32 -> bf16, layout-preserving) ----
__global__ __launch_bounds__(256) void cast_x_k(const float* __restrict__ in,
                                                unsigned short* __restrict__ out, int n) {
    int i = (blockIdx.x * 256 + threadIdx.x) * 4;
    if (i >= n) return;
    float4 v = *(const float4*)(in + i);
    ushort4 o;
    o.x = f2bf(v.x); o.y = f2bf(v.y); o.z = f2bf(v.z); o.w = f2bf(v.w);
    *(ushort4*)(out + i) = o;
}

// ---- cast + transpose weights via LDS tile (64x64): out[c][k] = in[k][c] ----
__global__ __launch_bounds__(256) void cast_wT_k(const float* __restrict__ w0, const float* __restrict__ w1,
                                                 const float* __restrict__ w2, const float* __restrict__ w3,
                                                 unsigned short* __restrict__ o0, unsigned short* __restrict__ o1,
                                                 unsigned short* __restrict__ o2, unsigned short* __restrict__ o3) {
    __shared__ unsigned short t[64][65];
    const float* in; unsigned short* out;
    switch (blockIdx.y) {
        case 0: in = w0; out = o0; break;
        case 1: in = w1; out = o1; break;
        case 2: in = w2; out = o2; break;
        default: in = w3; out = o3; break;
    }
    int kt = blockIdx.x / 12, ct = blockIdx.x % 12;
    int rr = threadIdx.x >> 4, cc = threadIdx.x & 15;
#pragma unroll
    for (int it = 0; it < 4; it++) {
        int row = kt * 64 + it * 16 + rr;
        int col = ct * 64 + cc * 4;
        float4 v = *(const float4*)(in + row * 768 + col);
        t[it * 16 + rr][cc * 4 + 0] = f2bf(v.x);
        t[it * 16 + rr][cc * 4 + 1] = f2bf(v.y);
        t[it * 16 + rr][cc * 4 + 2] = f2bf(v.z);
        t[it * 16 + rr][cc * 4 + 3] = f2bf(v.w);
    }
    __syncthreads();
#pragma unroll
    for (int it = 0; it < 4; it++) {
        int c_l = it * 16 + rr;
        int k_l = cc * 4;
        ushort4 o;
        o.x = t[k_l + 0][c_l];
        o.y = t[k_l + 1][c_l];
        o.z = t[k_l + 2][c_l];
        o.w = t[k_l + 3][c_l];
        *(ushort4*)(out + (ct * 64 + c_l) * 768 + kt * 64 + k_l) = o;
    }
}

// ---- fused QKV projection as one GEMM over N=2304; 3-buffer pipeline, counted vmcnt ----
__global__ __launch_bounds__(256) void qkv_gemm_k(
    const unsigned short* __restrict__ xb,
    const unsigned short* __restrict__ wqT, const unsigned short* __restrict__ wkT,
    const unsigned short* __restrict__ wvT,
    const float* __restrict__ bq, const float* __restrict__ bk, const float* __restrict__ bv,
    unsigned short* __restrict__ q, unsigned short* __restrict__ k, unsigned short* __restrict__ vT) {
    __shared__ unsigned short Abuf[3][128 * 32];
    __shared__ unsigned short Bbuf[3][128 * 32];

    int ctile = blockIdx.x;
    int mtile = blockIdx.y;
    int mat = ctile / 6;
    int col0 = (ctile % 6) * 128;
    const unsigned short* Bsrc = (mat == 0) ? wqT : ((mat == 1) ? wkT : wvT);
    const float* bias = (mat == 0) ? bq : ((mat == 1) ? bk : bv);

    int tid = threadIdx.x;
    int w = tid >> 6, l = tid & 63;
    int q16 = l & 15, g = l >> 4;
    int wr = w >> 1, wc = w & 1;

    int srow0 = tid >> 2;
    int ss = tid & 3;

    auto stage = [&](int tt, int buf) {
        int k0 = tt * 32;
#pragma unroll
        for (int i = 0; i < 2; ++i) {
            int row = srow0 + i * 64;
            int c16 = ss ^ ((row >> 1) & 3);
            glds16(xb + (mtile * 128 + row) * 768 + k0 + (c16 << 3),
                   (char*)&Abuf[buf][0] + i * 4096 + tid * 16);
            glds16(Bsrc + (col0 + row) * 768 + k0 + (c16 << 3),
                   (char*)&Bbuf[buf][0] + i * 4096 + tid * 16);
        }
    };

    v4f zero = {0.f, 0.f, 0.f, 0.f};
    v4f acc[4][4];
#pragma unroll
    for (int i = 0; i < 4; i++)
#pragma unroll
        for (int j = 0; j < 4; j++) acc[i][j] = zero;

    stage(0, 0);
    stage(1, 1);
    asm volatile("s_waitcnt vmcnt(4)" ::: "memory");
    __builtin_amdgcn_s_barrier();
    asm volatile("" ::: "memory");

    int rd = 0;
    for (int tt = 0; tt < 24; ++tt) {
        int st = rd + 2; if (st >= 3) st -= 3;
        if (tt + 2 < 24) stage(tt + 2, st);
        const char* Ab = (const char*)&Abuf[rd][0];
        const char* Bb = (const char*)&Bbuf[rd][0];
        v8s af[4], bf[4];
#pragma unroll
        for (int f = 0; f < 4; f++) {
            int arow = wr * 64 + f * 16 + q16;
            af[f] = *(const v8s*)(Ab + arow * 64 + ((g ^ ((arow >> 1) & 3)) << 4));
            int brow = wc * 64 + f * 16 + q16;
            bf[f] = *(const v8s*)(Bb + brow * 64 + ((g ^ ((brow >> 1) & 3)) << 4));
        }
#pragma unroll
        for (int i = 0; i < 4; i++)
#pragma unroll
            for (int j = 0; j < 4; j++)
                acc[i][j] = __builtin_amdgcn_mfma_f32_16x16x32_bf16(af[i], bf[j], acc[i][j], 0, 0, 0);
        asm volatile("s_waitcnt vmcnt(4)" ::: "memory");
        __builtin_amdgcn_s_barrier();
        asm volatile("" ::: "memory");
        rd = (rd + 1 == 3) ? 0 : rd + 1;
    }

    const float QSCL = 0.125f * 1.44269504088896340736f;
#pragma unroll
    for (int i = 0; i < 4; i++)
#pragma unroll
        for (int j = 0; j < 4; j++)
#pragma unroll
            for (int r = 0; r < 4; r++) {
                int gr = mtile * 128 + wr * 64 + i * 16 + 4 * g + r;
                int gcl = col0 + wc * 64 + j * 16 + q16;
                int b = gr / NN, n = gr % NN;
                int h = gcl / DH, d = gcl % DH;
                int bh = b * NH + h;
                float v = acc[i][j][r] + bias[gcl];
                if (mat == 0)      q[(bh * NN + n) * DH + d]  = f2bf(v * QSCL);
                else if (mat == 1) k[(bh * NN + n) * DH + d]  = f2bf(v);
                else               vT[(bh * DH + d) * NN + n] = f2bf(v);
            }
}

// ---- flash attention: SINGLE-WAVE blocks, zero barriers, counted vmcnt pipeline ----
// Wave owns 32 q-rows, sweeps kv 0..2048 in 64-tiles staged to its own LDS dbuf.
#define MKFRAG(PC, BASE, FR) {                                                     \
    int a0 = cvtpk(PC[BASE + 0], PC[BASE + 1]), a1 = cvtpk(PC[BASE + 2], PC[BASE + 3]); \
    int b0 = cvtpk(PC[BASE + 4], PC[BASE + 5]), b1 = cvtpk(PC[BASE + 6], PC[BASE + 7]); \
    int t0 = hi ? a0 : b0, t1 = hi ? a1 : b1;                                      \
    int r0 = __shfl_xor(t0, 32), r1 = __shfl_xor(t1, 32);                          \
    union { int i[4]; v8s s; } u_;                                                 \
    u_.i[0] = hi ? r0 : a0; u_.i[1] = hi ? r1 : a1;                                \
    u_.i[2] = hi ? b0 : r0; u_.i[3] = hi ? b1 : r1;                                \
    FR = u_.s; }

__global__ __launch_bounds__(64) void attn_k(
    const unsigned short* __restrict__ q, const unsigned short* __restrict__ k,
    const unsigned short* __restrict__ vT, unsigned short* __restrict__ z) {
    __shared__ __align__(16) char Kb[2][8192];   // K tile 64kv x 64d (128B rows, swizzled)
    __shared__ __align__(16) char Vb[2][8192];   // V^T tile 64d x 64kv (128B rows, swizzled)

    int bh = blockIdx.x % 24;                    // head -> fixed XCD class (24 % 8 == 0)
    int qt = blockIdx.x / 24;                    // 0..63, 32 q-rows each
    int b = bh / NH, h = bh % NH;
    int l = threadIdx.x;
    int hi = l >> 5, ln = l & 31;

    const unsigned short* qp = q + (size_t)bh * NN * DH;
    const unsigned short* kp = k + (size_t)bh * NN * DH;
    const unsigned short* vp = vT + (size_t)bh * DH * NN;

    int qrow = qt * 32 + ln;
    v8s qf[4];
#pragma unroll
    for (int ks = 0; ks < 4; ++ks)
        qf[ks] = *(const v8s*)(qp + qrow * DH + 16 * ks + 8 * hi);

    int cel = ((l & 7) ^ (l >> 3)) << 3;         // swizzled element offset within row
    int rb = l >> 3;                             // row base (0..7)

    auto stage = [&](int t, int buf) {
        int kv0 = t * 64;
        char* kd = &Kb[buf][0] + l * 16;
        char* vd = &Vb[buf][0] + l * 16;
#pragma unroll
        for (int i = 0; i < 8; ++i) {
            int row = i * 8 + rb;
            glds16(kp + (kv0 + row) * DH + cel, kd + i * 1024);
            glds16(vp + (size_t)row * NN + kv0 + cel, vd + i * 1024);
        }
    };

    v16f o0, o1;
#pragma unroll
    for (int i = 0; i < 16; i++) { o0[i] = 0.f; o1[i] = 0.f; }
    float mrow = -INFINITY, lsum = 0.f;

    stage(0, 0);

    int buf = 0;
    for (int t = 0; t < NN / 64; ++t) {
        if (t + 1 < NN / 64) {
            stage(t + 1, buf ^ 1);
            asm volatile("s_waitcnt vmcnt(16)" ::: "memory");
        } else {
            asm volatile("s_waitcnt vmcnt(0)" ::: "memory");
        }
        const char* kbp = &Kb[buf][0];
        const char* vbp = &Vb[buf][0];

        v16f s0, s1;
#pragma unroll
        for (int i = 0; i < 16; i++) { s0[i] = 0.f; s1[i] = 0.f; }

        // ---- QK^T: S^T[64 kv][32 q] ----
        {
            v8s kf0[4], kf1[4];
#pragma unroll
            for (int ks = 0; ks < 4; ++ks) {
                kf0[ks] = *(const v8s*)(kbp + ln * 128 + (((2 * ks + hi) ^ (ln & 7)) << 4));
                kf1[ks] = *(const v8s*)(kbp + (32 + ln) * 128 + (((2 * ks + hi) ^ (ln & 7)) << 4));
            }
            __builtin_amdgcn_s_setprio(1);
#pragma unroll
            for (int ks = 0; ks < 4; ++ks) {
                s0 = __builtin_amdgcn_mfma_f32_32x32x16_bf16(kf0[ks], qf[ks], s0, 0, 0, 0);
                s1 = __builtin_amdgcn_mfma_f32_32x32x16_bf16(kf1[ks], qf[ks], s1, 0, 0, 0);
            }
            __builtin_amdgcn_s_setprio(0);
        }

        // ---- online softmax (defer-max, THR=8) ----
        float vmax = -1e30f;
#pragma unroll
        for (int i = 0; i < 16; i++) vmax = fmaxf(vmax, fmaxf(s0[i], s1[i]));
        vmax = fmaxf(vmax, __shfl_xor(vmax, 32));

        if (!__all(vmax <= mrow + 8.f)) {
            float mn = fmaxf(mrow, vmax);
            float sc = exp2f(mrow - mn);
#pragma unroll
            for (int r = 0; r < 16; ++r) {
                int addr = 4 * ((r & 3) + 8 * (r >> 2)) + (hi << 4);
                float scr = __uint_as_float(
                    __builtin_amdgcn_ds_bpermute(addr, __float_as_uint(sc)));
                o0[r] *= scr; o1[r] *= scr;
            }
            lsum *= sc;
            mrow = mn;
        }

        float rs = 0.f;
#pragma unroll
        for (int i = 0; i < 16; i++) {
            s0[i] = exp2f(s0[i] - mrow);
            s1[i] = exp2f(s1[i] - mrow);
            rs += s0[i] + s1[i];
        }
        rs += __shfl_xor(rs, 32);
        lsum += rs;

        // ---- P fragments (in-register redistribution) ----
        v8s pf[4];
        MKFRAG(s0, 0, pf[0]);
        MKFRAG(s0, 8, pf[1]);
        MKFRAG(s1, 0, pf[2]);
        MKFRAG(s1, 8, pf[3]);

        // ---- PV: O[32 q][64 d] ----
        {
            v8s vf0[4], vf1[4];
#pragma unroll
            for (int ks = 0; ks < 4; ++ks) {
                vf0[ks] = *(const v8s*)(vbp + ln * 128 + (((2 * ks + hi) ^ (ln & 7)) << 4));
                vf1[ks] = *(const v8s*)(vbp + (32 + ln) * 128 + (((2 * ks + hi) ^ (ln & 7)) << 4));
            }
            __builtin_amdgcn_s_setprio(1);
#pragma unroll
            for (int ks = 0; ks < 4; ++ks) {
                o0 = __builtin_amdgcn_mfma_f32_32x32x16_bf16(pf[ks], vf0[ks], o0, 0, 0, 0);
                o1 = __builtin_amdgcn_mfma_f32_32x32x16_bf16(pf[ks], vf1[ks], o1, 0, 0, 0);
            }
            __builtin_amdgcn_s_setprio(0);
        }
        buf ^= 1;
    }

    float inv = 1.f / lsum;
#pragma unroll
    for (int r = 0; r < 16; ++r) {
        int addr = 4 * ((r & 3) + 8 * (r >> 2)) + (hi << 4);
        float ir = __uint_as_float(__builtin_amdgcn_ds_bpermute(addr, __float_as_uint(inv)));
        int qg = qt * 32 + (r & 3) + 8 * (r >> 2) + 4 * hi;
        size_t base = ((size_t)(b * NN + qg)) * DM + h * DH;
        z[base + ln]      = f2bf(o0[r] * ir);
        z[base + 32 + ln] = f2bf(o1[r] * ir);
    }
}

// ---- output projection: z[4096,768] @ wo + bo -> fp32; 3-buffer pipeline ----
__global__ __launch_bounds__(256) void out_gemm_k(
    const unsigned short* __restrict__ zb, const unsigned short* __restrict__ woT,
    const float* __restrict__ bo, float* __restrict__ out) {
    __shared__ unsigned short Abuf[3][128 * 32];
    __shared__ unsigned short Bbuf[3][128 * 32];

    int ctile = blockIdx.x;
    int mtile = blockIdx.y;
    int col0 = ctile * 128;

    int tid = threadIdx.x;
    int w = tid >> 6, l = tid & 63;
    int q16 = l & 15, g = l >> 4;
    int wr = w >> 1, wc = w & 1;

    int srow0 = tid >> 2;
    int ss = tid & 3;

    auto stage = [&](int tt, int buf) {
        int k0 = tt * 32;
#pragma unroll
        for (int i = 0; i < 2; ++i) {
            int row = srow0 + i * 64;
            int c16 = ss ^ ((row >> 1) & 3);
            glds16(zb + (mtile * 128 + row) * 768 + k0 + (c16 << 3),
                   (char*)&Abuf[buf][0] + i * 4096 + tid * 16);
            glds16(woT + (col0 + row) * 768 + k0 + (c16 << 3),
                   (char*)&Bbuf[buf][0] + i * 4096 + tid * 16);
        }
    };

    v4f zero = {0.f, 0.f, 0.f, 0.f};
    v4f acc[4][4];
#pragma unroll
    for (int i = 0; i < 4; i++)
#pragma unroll
        for (int j = 0; j < 4; j++) acc[i][j] = zero;

    stage(0, 0);
    stage(1, 1);
    asm volatile("s_waitcnt vmcnt(4)" ::: "memory");
    __builtin_amdgcn_s_barrier();
    asm volatile("" ::: "memory");

    int rd = 0;
    for (int tt = 0; tt < 24; ++tt) {
        int st = rd + 2; if (st >= 3) st -= 3;
        if (tt + 2 < 24) stage(tt + 2, st);
        const char* Ab = (const char*)&Abuf[rd][0];
        const char* Bb = (const char*)&Bbuf[rd][0];
        v8s af[4], bf[4];
#pragma unroll
        for (int f = 0; f < 4; f++) {
            int arow = wr * 64 + f * 16 + q16;
            af[f] = *(const v8s*)(Ab + arow * 64 + ((g ^ ((arow >> 1) & 3)) << 4));
            int brow = wc * 64 + f * 16 + q16;
            bf[f] = *(const v8s*)(Bb + brow * 64 + ((g ^ ((brow >> 1) & 3)) << 4));
        }
#pragma unroll
        for (int i = 0; i < 4; i++)
#pragma unroll
            for (int j = 0; j < 4; j++)
                acc[i][j] = __builtin_amdgcn_mfma_f32_16x16x32_bf16(af[i], bf[j], acc[i][j], 0, 0, 0);
        asm volatile("s_waitcnt vmcnt(4)" ::: "memory");
        __builtin_amdgcn_s_barrier();
        asm volatile("" ::: "memory");
        rd = (rd + 1 == 3) ? 0 : rd + 1;
    }

#pragma unroll
    for (int i = 0; i < 4; i++)
#pragma unroll
        for (int j = 0; j < 4; j++)
#pragma unroll
            for (int r = 0; r < 4; r++) {
                int gr = mtile * 128 + wr * 64 + i * 16 + 4 * g + r;
                int gc = col0 + wc * 64 + j * 16 + q16;
                out[gr * 768 + gc] = acc[i][j][r] + bo[gc];
            }
}

extern "C" void kernel_launch(void* const* d_in, const int* in_sizes, int n_in,
                              void* d_out, int out_size, void* d_ws, size_t ws_size,
                              hipStream_t stream) {
    const float* x  = (const float*)d_in[0];
    const float* wq = (const float*)d_in[1];
    const float* bq = (const float*)d_in[2];
    const float* wk = (const float*)d_in[3];
    const float* bk = (const float*)d_in[4];
    const float* wv = (const float*)d_in[5];
    const float* bv = (const float*)d_in[6];
    const float* wo = (const float*)d_in[7];
    const float* bo = (const float*)d_in[8];
    float* out = (float*)d_out;

    const int NX = BB * NN * DM;
    const int NW = 768 * 768;

    unsigned short* wsp = (unsigned short*)d_ws;
    unsigned short* xb  = wsp;
    unsigned short* wqT = xb + NX;
    unsigned short* wkT = wqT + NW;
    unsigned short* wvT = wkT + NW;
    unsigned short* woT = wvT + NW;
    unsigned short* qb  = woT + NW;
    unsigned short* kb  = qb + NX;
    unsigned short* vTb = kb + NX;
    unsigned short* zb  = vTb + NX;

    cast_x_k<<<NX / (256 * 4), 256, 0, stream>>>(x, xb, NX);
    cast_wT_k<<<dim3(144, 4), 256, 0, stream>>>(wq, wk, wv, wo, wqT, wkT, wvT, woT);
    qkv_gemm_k<<<dim3(18, 32), 256, 0, stream>>>(xb, wqT, wkT, wvT, bq, bk, bv, qb, kb, vTb);
    attn_k<<<24 * (NN / 32), 64, 0, stream>>>(qb, kb, vTb, zb);
    out_gemm_k<<<dim3(6, 32), 256, 0, stream>>>(zb, woT, bo, out);
}

// Round 9
// 176.399 us; speedup vs baseline: 1.1491x; 1.1491x over previous
//
#include <hip/hip_runtime.h>
#include <hip/hip_bf16.h>
#include <math.h>

#define NH 12
#define DH 64
#define BB 2
#define NN 2048
#define DM 768

typedef short v8s __attribute__((ext_vector_type(8)));
typedef float v4f __attribute__((ext_vector_type(4)));
typedef float v16f __attribute__((ext_vector_type(16)));

__device__ __forceinline__ unsigned short f2bf(float f) {
    union { float f; unsigned u; } x; x.f = f;
    unsigned r = x.u + 0x7fffu + ((x.u >> 16) & 1u);
    return (unsigned short)(r >> 16);
}

__device__ __forceinline__ int cvtpk(float lo, float hi2) {
    int r;
    asm("v_cvt_pk_bf16_f32 %0, %1, %2" : "=v"(r) : "v"(lo), "v"(hi2));
    return r;
}

__device__ __forceinline__ void glds16(const void* g, void* l) {
    __builtin_amdgcn_global_load_lds((const __attribute__((address_space(1))) void*)g,
                                     (__attribute__((address_space(3))) void*)l, 16, 0, 0);
}

// ---- cast x (fp32 -> bf16, layout-preserving) ----
__global__ __launch_bounds__(256) void cast_x_k(const float* __restrict__ in,
                                                unsigned short* __restrict__ out, int n) {
    int i = (blockIdx.x * 256 + threadIdx.x) * 4;
    if (i >= n) return;
    float4 v = *(const float4*)(in + i);
    ushort4 o;
    o.x = f2bf(v.x); o.y = f2bf(v.y); o.z = f2bf(v.z); o.w = f2bf(v.w);
    *(ushort4*)(out + i) = o;
}

// ---- cast + transpose weights via LDS tile (64x64): out[c][k] = in[k][c] ----
__global__ __launch_bounds__(256) void cast_wT_k(const float* __restrict__ w0, const float* __restrict__ w1,
                                                 const float* __restrict__ w2, const float* __restrict__ w3,
                                                 unsigned short* __restrict__ o0, unsigned short* __restrict__ o1,
                                                 unsigned short* __restrict__ o2, unsigned short* __restrict__ o3) {
    __shared__ unsigned short t[64][65];
    const float* in; unsigned short* out;
    switch (blockIdx.y) {
        case 0: in = w0; out = o0; break;
        case 1: in = w1; out = o1; break;
        case 2: in = w2; out = o2; break;
        default: in = w3; out = o3; break;
    }
    int kt = blockIdx.x / 12, ct = blockIdx.x % 12;
    int rr = threadIdx.x >> 4, cc = threadIdx.x & 15;
#pragma unroll
    for (int it = 0; it < 4; it++) {
        int row = kt * 64 + it * 16 + rr;
        int col = ct * 64 + cc * 4;
        float4 v = *(const float4*)(in + row * 768 + col);
        t[it * 16 + rr][cc * 4 + 0] = f2bf(v.x);
        t[it * 16 + rr][cc * 4 + 1] = f2bf(v.y);
        t[it * 16 + rr][cc * 4 + 2] = f2bf(v.z);
        t[it * 16 + rr][cc * 4 + 3] = f2bf(v.w);
    }
    __syncthreads();
#pragma unroll
    for (int it = 0; it < 4; it++) {
        int c_l = it * 16 + rr;
        int k_l = cc * 4;
        ushort4 o;
        o.x = t[k_l + 0][c_l];
        o.y = t[k_l + 1][c_l];
        o.z = t[k_l + 2][c_l];
        o.w = t[k_l + 3][c_l];
        *(ushort4*)(out + (ct * 64 + c_l) * 768 + kt * 64 + k_l) = o;
    }
}

// ---- fused QKV projection as one GEMM over N=2304; 3-buffer pipeline, counted vmcnt ----
__global__ __launch_bounds__(256) void qkv_gemm_k(
    const unsigned short* __restrict__ xb,
    const unsigned short* __restrict__ wqT, const unsigned short* __restrict__ wkT,
    const unsigned short* __restrict__ wvT,
    const float* __restrict__ bq, const float* __restrict__ bk, const float* __restrict__ bv,
    unsigned short* __restrict__ q, unsigned short* __restrict__ k, unsigned short* __restrict__ vT) {
    __shared__ unsigned short Abuf[3][128 * 32];
    __shared__ unsigned short Bbuf[3][128 * 32];

    int ctile = blockIdx.x;
    int mtile = blockIdx.y;
    int mat = ctile / 6;
    int col0 = (ctile % 6) * 128;
    const unsigned short* Bsrc = (mat == 0) ? wqT : ((mat == 1) ? wkT : wvT);
    const float* bias = (mat == 0) ? bq : ((mat == 1) ? bk : bv);

    int tid = threadIdx.x;
    int w = tid >> 6, l = tid & 63;
    int q16 = l & 15, g = l >> 4;
    int wr = w >> 1, wc = w & 1;

    int srow0 = tid >> 2;
    int ss = tid & 3;

    auto stage = [&](int tt, int buf) {
        int k0 = tt * 32;
#pragma unroll
        for (int i = 0; i < 2; ++i) {
            int row = srow0 + i * 64;
            int c16 = ss ^ ((row >> 1) & 3);
            glds16(xb + (mtile * 128 + row) * 768 + k0 + (c16 << 3),
                   (char*)&Abuf[buf][0] + i * 4096 + tid * 16);
            glds16(Bsrc + (col0 + row) * 768 + k0 + (c16 << 3),
                   (char*)&Bbuf[buf][0] + i * 4096 + tid * 16);
        }
    };

    v4f zero = {0.f, 0.f, 0.f, 0.f};
    v4f acc[4][4];
#pragma unroll
    for (int i = 0; i < 4; i++)
#pragma unroll
        for (int j = 0; j < 4; j++) acc[i][j] = zero;

    stage(0, 0);
    stage(1, 1);
    asm volatile("s_waitcnt vmcnt(4)" ::: "memory");
    __builtin_amdgcn_s_barrier();
    asm volatile("" ::: "memory");

    int rd = 0;
    for (int tt = 0; tt < 24; ++tt) {
        int st = rd + 2; if (st >= 3) st -= 3;
        if (tt + 2 < 24) stage(tt + 2, st);
        const char* Ab = (const char*)&Abuf[rd][0];
        const char* Bb = (const char*)&Bbuf[rd][0];
        v8s af[4], bf[4];
#pragma unroll
        for (int f = 0; f < 4; f++) {
            int arow = wr * 64 + f * 16 + q16;
            af[f] = *(const v8s*)(Ab + arow * 64 + ((g ^ ((arow >> 1) & 3)) << 4));
            int brow = wc * 64 + f * 16 + q16;
            bf[f] = *(const v8s*)(Bb + brow * 64 + ((g ^ ((brow >> 1) & 3)) << 4));
        }
#pragma unroll
        for (int i = 0; i < 4; i++)
#pragma unroll
            for (int j = 0; j < 4; j++)
                acc[i][j] = __builtin_amdgcn_mfma_f32_16x16x32_bf16(af[i], bf[j], acc[i][j], 0, 0, 0);
        asm volatile("s_waitcnt vmcnt(4)" ::: "memory");
        __builtin_amdgcn_s_barrier();
        asm volatile("" ::: "memory");
        rd = (rd + 1 == 3) ? 0 : rd + 1;
    }

    const float QSCL = 0.125f * 1.44269504088896340736f;
#pragma unroll
    for (int i = 0; i < 4; i++)
#pragma unroll
        for (int j = 0; j < 4; j++)
#pragma unroll
            for (int r = 0; r < 4; r++) {
                int gr = mtile * 128 + wr * 64 + i * 16 + 4 * g + r;
                int gcl = col0 + wc * 64 + j * 16 + q16;
                int b = gr / NN, n = gr % NN;
                int h = gcl / DH, d = gcl % DH;
                int bh = b * NH + h;
                float v = acc[i][j][r] + bias[gcl];
                if (mat == 0)      q[(bh * NN + n) * DH + d]  = f2bf(v * QSCL);
                else if (mat == 1) k[(bh * NN + n) * DH + d]  = f2bf(v);
                else               vT[(bh * DH + d) * NN + n] = f2bf(v);
            }
}

// ---- flash attention: 2 waves x 32 q-rows; QK^T pipelined one tile ahead ----
// iter t: [vmcnt(0); barrier] -> QK(t+1)->s_next -> stage(t+2) -> V-preload(t)
//         -> softmax(t) on s_cur (overlaps QK MFMA latency) -> PV(t).
// 3 LDS bufs: tile staged t-2, K-read t-1, V-read t, rewritten t+1 (barrier-separated).
#define MKFRAG(PC, BASE, FR) {                                                     \
    int a0 = cvtpk(PC[BASE + 0], PC[BASE + 1]), a1 = cvtpk(PC[BASE + 2], PC[BASE + 3]); \
    int b0 = cvtpk(PC[BASE + 4], PC[BASE + 5]), b1 = cvtpk(PC[BASE + 6], PC[BASE + 7]); \
    int t0 = hi ? a0 : b0, t1 = hi ? a1 : b1;                                      \
    int r0 = __shfl_xor(t0, 32), r1 = __shfl_xor(t1, 32);                          \
    union { int i[4]; v8s s; } u_;                                                 \
    u_.i[0] = hi ? r0 : a0; u_.i[1] = hi ? r1 : a1;                                \
    u_.i[2] = hi ? b0 : r0; u_.i[3] = hi ? b1 : r1;                                \
    FR = u_.s; }

__global__ __launch_bounds__(128) void attn_k(
    const unsigned short* __restrict__ q, const unsigned short* __restrict__ k,
    const unsigned short* __restrict__ vT, unsigned short* __restrict__ z) {
    __shared__ __align__(16) char Kb[3][8192];   // K tile 64kv x 64d (128B rows, swizzled)
    __shared__ __align__(16) char Vb[3][8192];   // V^T tile 64d x 64kv

    int bh = blockIdx.x % 24;
    int qt = blockIdx.x / 24;                    // 0..31 (64 q-rows per block)
    int b = bh / NH, h = bh % NH;
    int tid = threadIdx.x;
    int w = tid >> 6, l = tid & 63;
    int hi = l >> 5, ln = l & 31;

    const unsigned short* qp = q + (size_t)bh * NN * DH;
    const unsigned short* kp = k + (size_t)bh * NN * DH;
    const unsigned short* vp = vT + (size_t)bh * DH * NN;

    int qrow = qt * 64 + w * 32 + ln;
    v8s qf[4];
#pragma unroll
    for (int ks = 0; ks < 4; ++ks)
        qf[ks] = *(const v8s*)(qp + qrow * DH + 16 * ks + 8 * hi);

    // cooperative staging: 128 threads cover 512 16B slots of K and of V
    auto stage = [&](int t, int buf) {
        int kv0 = t * 64;
#pragma unroll
        for (int i = 0; i < 4; ++i) {
            int slot = tid + 128 * i;
            int row = slot >> 3;
            int c16 = (slot & 7) ^ (row & 7);
            glds16(kp + (kv0 + row) * DH + (c16 << 3), &Kb[buf][0] + slot * 16);
            glds16(vp + (size_t)row * NN + kv0 + (c16 << 3), &Vb[buf][0] + slot * 16);
        }
    };

    auto qkt = [&](int buf, v16f& d0, v16f& d1) {
        const char* kbp = &Kb[buf][0];
        v8s kf0[4], kf1[4];
#pragma unroll
        for (int ks = 0; ks < 4; ++ks) {
            kf0[ks] = *(const v8s*)(kbp + ln * 128 + (((2 * ks + hi) ^ (ln & 7)) << 4));
            kf1[ks] = *(const v8s*)(kbp + (32 + ln) * 128 + (((2 * ks + hi) ^ (ln & 7)) << 4));
        }
#pragma unroll
        for (int i = 0; i < 16; i++) { d0[i] = 0.f; d1[i] = 0.f; }
        __builtin_amdgcn_s_setprio(1);
#pragma unroll
        for (int ks = 0; ks < 4; ++ks) {
            d0 = __builtin_amdgcn_mfma_f32_32x32x16_bf16(kf0[ks], qf[ks], d0, 0, 0, 0);
            d1 = __builtin_amdgcn_mfma_f32_32x32x16_bf16(kf1[ks], qf[ks], d1, 0, 0, 0);
        }
        __builtin_amdgcn_s_setprio(0);
    };

    v16f o0, o1;
#pragma unroll
    for (int i = 0; i < 16; i++) { o0[i] = 0.f; o1[i] = 0.f; }
    float mrow = -INFINITY, lsum = 0.f;
    v16f sA0, sA1, sB0, sB1;

    stage(0, 0);
    stage(1, 1);
    asm volatile("s_waitcnt vmcnt(8)" ::: "memory");   // stage(0) landed (own wave)
    __builtin_amdgcn_s_barrier();                      // publish stage(0)
    asm volatile("" ::: "memory");
    qkt(0, sA0, sA1);                                  // S(0)

    auto iter = [&](int T, v16f& sc0, v16f& sc1, v16f& sn0, v16f& sn1) {
        asm volatile("s_waitcnt vmcnt(0)" ::: "memory");  // stage(T+1) landed (issued iter T-1)
        __builtin_amdgcn_s_barrier();                     // publish; all waves done reading buf T-1
        asm volatile("" ::: "memory");

        if (T + 1 < 32) {
            int nb = T + 1; nb -= (nb >= 3) ? 3 : 0; nb -= (nb >= 3) ? 3 : 0;
            qkt((T + 1) % 3, sn0, sn1);                   // QK(T+1), in flight under softmax(T)
        }
        if (T + 2 < 32) stage(T + 2, (T + 2) % 3);

        // V fragments for tile T (ds_reads hide under softmax VALU)
        const char* vbp = &Vb[T % 3][0];
        v8s vf0[4], vf1[4];
#pragma unroll
        for (int ks = 0; ks < 4; ++ks) {
            vf0[ks] = *(const v8s*)(vbp + ln * 128 + (((2 * ks + hi) ^ (ln & 7)) << 4));
            vf1[ks] = *(const v8s*)(vbp + (32 + ln) * 128 + (((2 * ks + hi) ^ (ln & 7)) << 4));
        }

        // ---- softmax(T) on sc (4 parallel reduction chains) ----
        float va = -1e30f, vb2 = -1e30f, vc2 = -1e30f, vd2 = -1e30f;
#pragma unroll
        for (int i = 0; i < 16; i += 4) {
            va = fmaxf(va, sc0[i]);      vb2 = fmaxf(vb2, sc0[i + 1]);
            vc2 = fmaxf(vc2, sc0[i + 2]); vd2 = fmaxf(vd2, sc0[i + 3]);
            va = fmaxf(va, sc1[i]);      vb2 = fmaxf(vb2, sc1[i + 1]);
            vc2 = fmaxf(vc2, sc1[i + 2]); vd2 = fmaxf(vd2, sc1[i + 3]);
        }
        float vmax = fmaxf(fmaxf(va, vb2), fmaxf(vc2, vd2));
        vmax = fmaxf(vmax, __shfl_xor(vmax, 32));

        if (!__all(vmax <= mrow + 8.f)) {                 // defer-max (THR=8)
            float mn = fmaxf(mrow, vmax);
            float sc = exp2f(mrow - mn);
#pragma unroll
            for (int r = 0; r < 16; ++r) {
                int addr = 4 * ((r & 3) + 8 * (r >> 2)) + (hi << 4);
                float scr = __uint_as_float(
                    __builtin_amdgcn_ds_bpermute(addr, __float_as_uint(sc)));
                o0[r] *= scr; o1[r] *= scr;
            }
            lsum *= sc;
            mrow = mn;
        }

        float r0 = 0.f, r1 = 0.f, r2 = 0.f, r3 = 0.f;
#pragma unroll
        for (int i = 0; i < 16; i += 4) {
            sc0[i] = exp2f(sc0[i] - mrow);     sc0[i + 1] = exp2f(sc0[i + 1] - mrow);
            sc0[i + 2] = exp2f(sc0[i + 2] - mrow); sc0[i + 3] = exp2f(sc0[i + 3] - mrow);
            sc1[i] = exp2f(sc1[i] - mrow);     sc1[i + 1] = exp2f(sc1[i + 1] - mrow);
            sc1[i + 2] = exp2f(sc1[i + 2] - mrow); sc1[i + 3] = exp2f(sc1[i + 3] - mrow);
            r0 += sc0[i] + sc1[i];       r1 += sc0[i + 1] + sc1[i + 1];
            r2 += sc0[i + 2] + sc1[i + 2]; r3 += sc0[i + 3] + sc1[i + 3];
        }
        float rs = (r0 + r1) + (r2 + r3);
        rs += __shfl_xor(rs, 32);
        lsum += rs;

        v8s pf[4];
        MKFRAG(sc0, 0, pf[0]);
        MKFRAG(sc0, 8, pf[1]);
        MKFRAG(sc1, 0, pf[2]);
        MKFRAG(sc1, 8, pf[3]);

        __builtin_amdgcn_s_setprio(1);
#pragma unroll
        for (int ks = 0; ks < 4; ++ks) {
            o0 = __builtin_amdgcn_mfma_f32_32x32x16_bf16(pf[ks], vf0[ks], o0, 0, 0, 0);
            o1 = __builtin_amdgcn_mfma_f32_32x32x16_bf16(pf[ks], vf1[ks], o1, 0, 0, 0);
        }
        __builtin_amdgcn_s_setprio(0);
    };

    for (int T = 0; T < 32; T += 2) {
        iter(T, sA0, sA1, sB0, sB1);
        iter(T + 1, sB0, sB1, sA0, sA1);
    }

    float inv = 1.f / lsum;
#pragma unroll
    for (int r = 0; r < 16; ++r) {
        int addr = 4 * ((r & 3) + 8 * (r >> 2)) + (hi << 4);
        float ir = __uint_as_float(__builtin_amdgcn_ds_bpermute(addr, __float_as_uint(inv)));
        int qg = qt * 64 + w * 32 + (r & 3) + 8 * (r >> 2) + 4 * hi;
        size_t base = ((size_t)(b * NN + qg)) * DM + h * DH;
        z[base + ln]      = f2bf(o0[r] * ir);
        z[base + 32 + ln] = f2bf(o1[r] * ir);
    }
}

// ---- output projection: z[4096,768] @ wo + bo -> fp32; 3-buffer pipeline ----
__global__ __launch_bounds__(256) void out_gemm_k(
    const unsigned short* __restrict__ zb, const unsigned short* __restrict__ woT,
    const float* __restrict__ bo, float* __restrict__ out) {
    __shared__ unsigned short Abuf[3][128 * 32];
    __shared__ unsigned short Bbuf[3][128 * 32];

    int ctile = blockIdx.x;
    int mtile = blockIdx.y;
    int col0 = ctile * 128;

    int tid = threadIdx.x;
    int w = tid >> 6, l = tid & 63;
    int q16 = l & 15, g = l >> 4;
    int wr = w >> 1, wc = w & 1;

    int srow0 = tid >> 2;
    int ss = tid & 3;

    auto stage = [&](int tt, int buf) {
        int k0 = tt * 32;
#pragma unroll
        for (int i = 0; i < 2; ++i) {
            int row = srow0 + i * 64;
            int c16 = ss ^ ((row >> 1) & 3);
            glds16(zb + (mtile * 128 + row) * 768 + k0 + (c16 << 3),
                   (char*)&Abuf[buf][0] + i * 4096 + tid * 16);
            glds16(woT + (col0 + row) * 768 + k0 + (c16 << 3),
                   (char*)&Bbuf[buf][0] + i * 4096 + tid * 16);
        }
    };

    v4f zero = {0.f, 0.f, 0.f, 0.f};
    v4f acc[4][4];
#pragma unroll
    for (int i = 0; i < 4; i++)
#pragma unroll
        for (int j = 0; j < 4; j++) acc[i][j] = zero;

    stage(0, 0);
    stage(1, 1);
    asm volatile("s_waitcnt vmcnt(4)" ::: "memory");
    __builtin_amdgcn_s_barrier();
    asm volatile("" ::: "memory");

    int rd = 0;
    for (int tt = 0; tt < 24; ++tt) {
        int st = rd + 2; if (st >= 3) st -= 3;
        if (tt + 2 < 24) stage(tt + 2, st);
        const char* Ab = (const char*)&Abuf[rd][0];
        const char* Bb = (const char*)&Bbuf[rd][0];
        v8s af[4], bf[4];
#pragma unroll
        for (int f = 0; f < 4; f++) {
            int arow = wr * 64 + f * 16 + q16;
            af[f] = *(const v8s*)(Ab + arow * 64 + ((g ^ ((arow >> 1) & 3)) << 4));
            int brow = wc * 64 + f * 16 + q16;
            bf[f] = *(const v8s*)(Bb + brow * 64 + ((g ^ ((brow >> 1) & 3)) << 4));
        }
#pragma unroll
        for (int i = 0; i < 4; i++)
#pragma unroll
            for (int j = 0; j < 4; j++)
                acc[i][j] = __builtin_amdgcn_mfma_f32_16x16x32_bf16(af[i], bf[j], acc[i][j], 0, 0, 0);
        asm volatile("s_waitcnt vmcnt(4)" ::: "memory");
        __builtin_amdgcn_s_barrier();
        asm volatile("" ::: "memory");
        rd = (rd + 1 == 3) ? 0 : rd + 1;
    }

#pragma unroll
    for (int i = 0; i < 4; i++)
#pragma unroll
        for (int j = 0; j < 4; j++)
#pragma unroll
            for (int r = 0; r < 4; r++) {
                int gr = mtile * 128 + wr * 64 + i * 16 + 4 * g + r;
                int gc = col0 + wc * 64 + j * 16 + q16;
                out[gr * 768 + gc] = acc[i][j][r] + bo[gc];
            }
}

extern "C" void kernel_launch(void* const* d_in, const int* in_sizes, int n_in,
                              void* d_out, int out_size, void* d_ws, size_t ws_size,
                              hipStream_t stream) {
    const float* x  = (const float*)d_in[0];
    const float* wq = (const float*)d_in[1];
    const float* bq = (const float*)d_in[2];
    const float* wk = (const float*)d_in[3];
    const float* bk = (const float*)d_in[4];
    const float* wv = (const float*)d_in[5];
    const float* bv = (const float*)d_in[6];
    const float* wo = (const float*)d_in[7];
    const float* bo = (const float*)d_in[8];
    float* out = (float*)d_out;

    const int NX = BB * NN * DM;
    const int NW = 768 * 768;

    unsigned short* wsp = (unsigned short*)d_ws;
    unsigned short* xb  = wsp;
    unsigned short* wqT = xb + NX;
    unsigned short* wkT = wqT + NW;
    unsigned short* wvT = wkT + NW;
    unsigned short* woT = wvT + NW;
    unsigned short* qb  = woT + NW;
    unsigned short* kb  = qb + NX;
    unsigned short* vTb = kb + NX;
    unsigned short* zb  = vTb + NX;

    cast_x_k<<<NX / (256 * 4), 256, 0, stream>>>(x, xb, NX);
    cast_wT_k<<<dim3(144, 4), 256, 0, stream>>>(wq, wk, wv, wo, wqT, wkT, wvT, woT);
    qkv_gemm_k<<<dim3(18, 32), 256, 0, stream>>>(xb, wqT, wkT, wvT, bq, bk, bv, qb, kb, vTb);
    attn_k<<<24 * (NN / 64), 128, 0, stream>>>(qb, kb, vTb, zb);
    out_gemm_k<<<dim3(6, 32), 256, 0, stream>>>(zb, woT, bo, out);
}

// Round 10
// 130.728 us; speedup vs baseline: 1.5506x; 1.3494x over previous
//
#include <hip/hip_runtime.h>
#include <hip/hip_bf16.h>
#include <math.h>

#define NH 12
#define DH 64
#define BB 2
#define NN 2048
#define DM 768

typedef short v8s __attribute__((ext_vector_type(8)));
typedef float v4f __attribute__((ext_vector_type(4)));

__device__ __forceinline__ unsigned short f2bf(float f) {
    union { float f; unsigned u; } x; x.f = f;
    unsigned r = x.u + 0x7fffu + ((x.u >> 16) & 1u);
    return (unsigned short)(r >> 16);
}

__device__ __forceinline__ int cvtpk(float lo, float hi2) {
    int r;
    asm("v_cvt_pk_bf16_f32 %0, %1, %2" : "=v"(r) : "v"(lo), "v"(hi2));
    return r;
}

__device__ __forceinline__ void glds16(const void* g, void* l) {
    __builtin_amdgcn_global_load_lds((const __attribute__((address_space(1))) void*)g,
                                     (__attribute__((address_space(3))) void*)l, 16, 0, 0);
}

// ---- cast x (fp32 -> bf16, layout-preserving) ----
__global__ __launch_bounds__(256) void cast_x_k(const float* __restrict__ in,
                                                unsigned short* __restrict__ out, int n) {
    int i = (blockIdx.x * 256 + threadIdx.x) * 4;
    if (i >= n) return;
    float4 v = *(const float4*)(in + i);
    ushort4 o;
    o.x = f2bf(v.x); o.y = f2bf(v.y); o.z = f2bf(v.z); o.w = f2bf(v.w);
    *(ushort4*)(out + i) = o;
}

// ---- cast + transpose weights via LDS tile (64x64): out[c][k] = in[k][c] ----
__global__ __launch_bounds__(256) void cast_wT_k(const float* __restrict__ w0, const float* __restrict__ w1,
                                                 const float* __restrict__ w2, const float* __restrict__ w3,
                                                 unsigned short* __restrict__ o0, unsigned short* __restrict__ o1,
                                                 unsigned short* __restrict__ o2, unsigned short* __restrict__ o3) {
    __shared__ unsigned short t[64][65];
    const float* in; unsigned short* out;
    switch (blockIdx.y) {
        case 0: in = w0; out = o0; break;
        case 1: in = w1; out = o1; break;
        case 2: in = w2; out = o2; break;
        default: in = w3; out = o3; break;
    }
    int kt = blockIdx.x / 12, ct = blockIdx.x % 12;
    int rr = threadIdx.x >> 4, cc = threadIdx.x & 15;
#pragma unroll
    for (int it = 0; it < 4; it++) {
        int row = kt * 64 + it * 16 + rr;
        int col = ct * 64 + cc * 4;
        float4 v = *(const float4*)(in + row * 768 + col);
        t[it * 16 + rr][cc * 4 + 0] = f2bf(v.x);
        t[it * 16 + rr][cc * 4 + 1] = f2bf(v.y);
        t[it * 16 + rr][cc * 4 + 2] = f2bf(v.z);
        t[it * 16 + rr][cc * 4 + 3] = f2bf(v.w);
    }
    __syncthreads();
#pragma unroll
    for (int it = 0; it < 4; it++) {
        int c_l = it * 16 + rr;
        int k_l = cc * 4;
        ushort4 o;
        o.x = t[k_l + 0][c_l];
        o.y = t[k_l + 1][c_l];
        o.z = t[k_l + 2][c_l];
        o.w = t[k_l + 3][c_l];
        *(ushort4*)(out + (ct * 64 + c_l) * 768 + kt * 64 + k_l) = o;
    }
}

// ---- fused QKV projection as one GEMM over N=2304; 3-buffer pipeline, counted vmcnt ----
__global__ __launch_bounds__(256) void qkv_gemm_k(
    const unsigned short* __restrict__ xb,
    const unsigned short* __restrict__ wqT, const unsigned short* __restrict__ wkT,
    const unsigned short* __restrict__ wvT,
    const float* __restrict__ bq, const float* __restrict__ bk, const float* __restrict__ bv,
    unsigned short* __restrict__ q, unsigned short* __restrict__ k, unsigned short* __restrict__ vT) {
    __shared__ unsigned short Abuf[3][128 * 32];
    __shared__ unsigned short Bbuf[3][128 * 32];

    int ctile = blockIdx.x;
    int mtile = blockIdx.y;
    int mat = ctile / 6;
    int col0 = (ctile % 6) * 128;
    const unsigned short* Bsrc = (mat == 0) ? wqT : ((mat == 1) ? wkT : wvT);
    const float* bias = (mat == 0) ? bq : ((mat == 1) ? bk : bv);

    int tid = threadIdx.x;
    int w = tid >> 6, l = tid & 63;
    int q16 = l & 15, g = l >> 4;
    int wr = w >> 1, wc = w & 1;

    int srow0 = tid >> 2;
    int ss = tid & 3;

    auto stage = [&](int tt, int buf) {
        int k0 = tt * 32;
#pragma unroll
        for (int i = 0; i < 2; ++i) {
            int row = srow0 + i * 64;
            int c16 = ss ^ ((row >> 1) & 3);
            glds16(xb + (mtile * 128 + row) * 768 + k0 + (c16 << 3),
                   (char*)&Abuf[buf][0] + i * 4096 + tid * 16);
            glds16(Bsrc + (col0 + row) * 768 + k0 + (c16 << 3),
                   (char*)&Bbuf[buf][0] + i * 4096 + tid * 16);
        }
    };

    v4f zero = {0.f, 0.f, 0.f, 0.f};
    v4f acc[4][4];
#pragma unroll
    for (int i = 0; i < 4; i++)
#pragma unroll
        for (int j = 0; j < 4; j++) acc[i][j] = zero;

    stage(0, 0);
    stage(1, 1);
    asm volatile("s_waitcnt vmcnt(4)" ::: "memory");
    __builtin_amdgcn_s_barrier();
    asm volatile("" ::: "memory");

    int rd = 0;
    for (int tt = 0; tt < 24; ++tt) {
        int st = rd + 2; if (st >= 3) st -= 3;
        if (tt + 2 < 24) stage(tt + 2, st);
        const char* Ab = (const char*)&Abuf[rd][0];
        const char* Bb = (const char*)&Bbuf[rd][0];
        v8s af[4], bf[4];
#pragma unroll
        for (int f = 0; f < 4; f++) {
            int arow = wr * 64 + f * 16 + q16;
            af[f] = *(const v8s*)(Ab + arow * 64 + ((g ^ ((arow >> 1) & 3)) << 4));
            int brow = wc * 64 + f * 16 + q16;
            bf[f] = *(const v8s*)(Bb + brow * 64 + ((g ^ ((brow >> 1) & 3)) << 4));
        }
#pragma unroll
        for (int i = 0; i < 4; i++)
#pragma unroll
            for (int j = 0; j < 4; j++)
                acc[i][j] = __builtin_amdgcn_mfma_f32_16x16x32_bf16(af[i], bf[j], acc[i][j], 0, 0, 0);
        asm volatile("s_waitcnt vmcnt(4)" ::: "memory");
        __builtin_amdgcn_s_barrier();
        asm volatile("" ::: "memory");
        rd = (rd + 1 == 3) ? 0 : rd + 1;
    }

    const float QSCL = 0.125f * 1.44269504088896340736f;
#pragma unroll
    for (int i = 0; i < 4; i++)
#pragma unroll
        for (int j = 0; j < 4; j++)
#pragma unroll
            for (int r = 0; r < 4; r++) {
                int gr = mtile * 128 + wr * 64 + i * 16 + 4 * g + r;
                int gcl = col0 + wc * 64 + j * 16 + q16;
                int b = gr / NN, n = gr % NN;
                int h = gcl / DH, d = gcl % DH;
                int bh = b * NH + h;
                float v = acc[i][j][r] + bias[gcl];
                if (mat == 0)      q[(bh * NN + n) * DH + d]  = f2bf(v * QSCL);
                else if (mat == 1) k[(bh * NN + n) * DH + d]  = f2bf(v);
                else               vT[(bh * DH + d) * NN + n] = f2bf(v);
            }
}

// ---- flash attention: R4 structure (4 waves x 16q, LDS-staged K/V dbuf, swapped MFMA)
//      + surgical VALU cuts: cvt_pk P-pack, defer-max rescale, lsum via ones-MFMA ----
__global__ __launch_bounds__(256) void attn_k(
    const unsigned short* __restrict__ q, const unsigned short* __restrict__ k,
    const unsigned short* __restrict__ vT, unsigned short* __restrict__ z) {
    __shared__ unsigned short Kbuf[2][64 * 64];
    __shared__ unsigned short Vbuf[2][64 * 64];
    __shared__ unsigned short plds[4][16][72];

    int bh = blockIdx.x % 24;
    int qt = blockIdx.x / 24;
    int b = bh / NH, h = bh % NH;
    int w = threadIdx.x >> 6, l = threadIdx.x & 63;
    int q16 = l & 15, g = l >> 4;
    const unsigned short* qp = q + (size_t)bh * NN * DH;
    const unsigned short* kp = k + (size_t)bh * NN * DH;
    const unsigned short* vp = vT + (size_t)bh * DH * NN;
    int qrow = qt * 64 + w * 16 + q16;

    v8s qf0 = *(const v8s*)(qp + qrow * DH + 8 * g);
    v8s qf1 = *(const v8s*)(qp + qrow * DH + 32 + 8 * g);

    v8s ones;
#pragma unroll
    for (int i = 0; i < 8; i++) ones[i] = (short)0x3F80;   // bf16 1.0

    int sY = w * 2048 + l * 16;
    int srow0 = sY >> 7;
    int ss = (sY >> 4) & 7;

    auto stage = [&](int t, int buf) {
        int kv = t * 64;
#pragma unroll
        for (int i = 0; i < 2; ++i) {
            int row = srow0 + i * 8;
            int c16 = ss ^ (row & 7);
            char* kdst = (char*)&Kbuf[buf][0] + w * 2048 + i * 1024;
            char* vdst = (char*)&Vbuf[buf][0] + w * 2048 + i * 1024;
            glds16(kp + (kv + row) * DH + (c16 << 3), kdst);
            glds16(vp + row * NN + kv + (c16 << 3), vdst);
        }
    };

    v4f zero = {0.f, 0.f, 0.f, 0.f};
    float mrow = -INFINITY;
    v4f o[4];
    v4f osum = zero;                       // [0] accumulates sum(P) per q-row via ones-MFMA
#pragma unroll
    for (int dt = 0; dt < 4; dt++) o[dt] = zero;

    stage(0, 0);
    __syncthreads();

    for (int t = 0; t < NN / 64; ++t) {
        int cur = t & 1;
        if (t + 1 < NN / 64) stage(t + 1, cur ^ 1);

        const char* kb = (const char*)&Kbuf[cur][0];
        const char* vb = (const char*)&Vbuf[cur][0];

        v4f st[4];
#pragma unroll
        for (int ct = 0; ct < 4; ct++) {
            int krow = ct * 16 + q16;
            v8s kf0 = *(const v8s*)(kb + krow * 128 + ((g ^ (krow & 7)) << 4));
            v8s kf1 = *(const v8s*)(kb + krow * 128 + (((4 + g) ^ (krow & 7)) << 4));
            st[ct] = __builtin_amdgcn_mfma_f32_16x16x32_bf16(kf0, qf0, zero, 0, 0, 0);
            st[ct] = __builtin_amdgcn_mfma_f32_16x16x32_bf16(kf1, qf1, st[ct], 0, 0, 0);
        }

        // in-lane max over 16 values (max3-friendly nesting), then 2 shuffles across g-groups
        float ma = fmaxf(fmaxf(st[0][0], st[0][1]), st[0][2]);
        float mb = fmaxf(fmaxf(st[0][3], st[1][0]), st[1][1]);
        float mc = fmaxf(fmaxf(st[1][2], st[1][3]), st[2][0]);
        float md = fmaxf(fmaxf(st[2][1], st[2][2]), st[2][3]);
        float me = fmaxf(fmaxf(st[3][0], st[3][1]), st[3][2]);
        float vmax = fmaxf(fmaxf(ma, mb), mc);
        vmax = fmaxf(fmaxf(vmax, md), fmaxf(me, st[3][3]));
        vmax = fmaxf(vmax, __shfl_xor(vmax, 16));
        vmax = fmaxf(vmax, __shfl_xor(vmax, 32));

        // defer-max: rescale only when the running max grew by more than 8 (log2 domain)
        if (!__all(vmax <= mrow + 8.f)) {
            float mn = fmaxf(mrow, vmax);
            float sc = exp2f(mrow - mn);
#pragma unroll
            for (int dt = 0; dt < 4; dt++)
#pragma unroll
                for (int r = 0; r < 4; r++) o[dt][r] *= sc;
            osum[0] *= sc;
            mrow = mn;
        }

        // exp + pack to bf16 (cvt_pk) + P bounce through padded LDS
#pragma unroll
        for (int ct = 0; ct < 4; ct++) {
            float p0 = exp2f(st[ct][0] - mrow);
            float p1 = exp2f(st[ct][1] - mrow);
            float p2 = exp2f(st[ct][2] - mrow);
            float p3 = exp2f(st[ct][3] - mrow);
            union { int i[2]; short4 s; } u;
            u.i[0] = cvtpk(p0, p1);
            u.i[1] = cvtpk(p2, p3);
            *(short4*)(&plds[w][q16][ct * 16 + 4 * g]) = u.s;
        }

        v8s pf0 = *(const v8s*)(&plds[w][q16][8 * g]);
        v8s pf1 = *(const v8s*)(&plds[w][q16][32 + 8 * g]);

        // lsum via ones-MFMA (matrix pipe, replaces 16 VALU adds + 2 shuffles)
        osum = __builtin_amdgcn_mfma_f32_16x16x32_bf16(ones, pf0, osum, 0, 0, 0);
        osum = __builtin_amdgcn_mfma_f32_16x16x32_bf16(ones, pf1, osum, 0, 0, 0);

#pragma unroll
        for (int dt = 0; dt < 4; dt++) {
            int dcol = dt * 16 + q16;
            v8s vf0 = *(const v8s*)(vb + dcol * 128 + ((g ^ (dcol & 7)) << 4));
            v8s vf1 = *(const v8s*)(vb + dcol * 128 + (((4 + g) ^ (dcol & 7)) << 4));
            o[dt] = __builtin_amdgcn_mfma_f32_16x16x32_bf16(vf0, pf0, o[dt], 0, 0, 0);
            o[dt] = __builtin_amdgcn_mfma_f32_16x16x32_bf16(vf1, pf1, o[dt], 0, 0, 0);
        }
        __syncthreads();
    }

    float inv = 1.f / osum[0];
    int n = qt * 64 + w * 16 + q16;
#pragma unroll
    for (int dt = 0; dt < 4; dt++) {
        short4 s4;
        s4.x = (short)f2bf(o[dt][0] * inv);
        s4.y = (short)f2bf(o[dt][1] * inv);
        s4.z = (short)f2bf(o[dt][2] * inv);
        s4.w = (short)f2bf(o[dt][3] * inv);
        *(short4*)(&z[((size_t)(b * NN + n)) * DM + h * DH + dt * 16 + 4 * g]) = s4;
    }
}

// ---- output projection: z[4096,768] @ wo + bo -> fp32; 3-buffer pipeline ----
__global__ __launch_bounds__(256) void out_gemm_k(
    const unsigned short* __restrict__ zb, const unsigned short* __restrict__ woT,
    const float* __restrict__ bo, float* __restrict__ out) {
    __shared__ unsigned short Abuf[3][128 * 32];
    __shared__ unsigned short Bbuf[3][128 * 32];

    int ctile = blockIdx.x;
    int mtile = blockIdx.y;
    int col0 = ctile * 128;

    int tid = threadIdx.x;
    int w = tid >> 6, l = tid & 63;
    int q16 = l & 15, g = l >> 4;
    int wr = w >> 1, wc = w & 1;

    int srow0 = tid >> 2;
    int ss = tid & 3;

    auto stage = [&](int tt, int buf) {
        int k0 = tt * 32;
#pragma unroll
        for (int i = 0; i < 2; ++i) {
            int row = srow0 + i * 64;
            int c16 = ss ^ ((row >> 1) & 3);
            glds16(zb + (mtile * 128 + row) * 768 + k0 + (c16 << 3),
                   (char*)&Abuf[buf][0] + i * 4096 + tid * 16);
            glds16(woT + (col0 + row) * 768 + k0 + (c16 << 3),
                   (char*)&Bbuf[buf][0] + i * 4096 + tid * 16);
        }
    };

    v4f zero = {0.f, 0.f, 0.f, 0.f};
    v4f acc[4][4];
#pragma unroll
    for (int i = 0; i < 4; i++)
#pragma unroll
        for (int j = 0; j < 4; j++) acc[i][j] = zero;

    stage(0, 0);
    stage(1, 1);
    asm volatile("s_waitcnt vmcnt(4)" ::: "memory");
    __builtin_amdgcn_s_barrier();
    asm volatile("" ::: "memory");

    int rd = 0;
    for (int tt = 0; tt < 24; ++tt) {
        int st = rd + 2; if (st >= 3) st -= 3;
        if (tt + 2 < 24) stage(tt + 2, st);
        const char* Ab = (const char*)&Abuf[rd][0];
        const char* Bb = (const char*)&Bbuf[rd][0];
        v8s af[4], bf[4];
#pragma unroll
        for (int f = 0; f < 4; f++) {
            int arow = wr * 64 + f * 16 + q16;
            af[f] = *(const v8s*)(Ab + arow * 64 + ((g ^ ((arow >> 1) & 3)) << 4));
            int brow = wc * 64 + f * 16 + q16;
            bf[f] = *(const v8s*)(Bb + brow * 64 + ((g ^ ((brow >> 1) & 3)) << 4));
        }
#pragma unroll
        for (int i = 0; i < 4; i++)
#pragma unroll
            for (int j = 0; j < 4; j++)
                acc[i][j] = __builtin_amdgcn_mfma_f32_16x16x32_bf16(af[i], bf[j], acc[i][j], 0, 0, 0);
        asm volatile("s_waitcnt vmcnt(4)" ::: "memory");
        __builtin_amdgcn_s_barrier();
        asm volatile("" ::: "memory");
        rd = (rd + 1 == 3) ? 0 : rd + 1;
    }

#pragma unroll
    for (int i = 0; i < 4; i++)
#pragma unroll
        for (int j = 0; j < 4; j++)
#pragma unroll
            for (int r = 0; r < 4; r++) {
                int gr = mtile * 128 + wr * 64 + i * 16 + 4 * g + r;
                int gc = col0 + wc * 64 + j * 16 + q16;
                out[gr * 768 + gc] = acc[i][j][r] + bo[gc];
            }
}

extern "C" void kernel_launch(void* const* d_in, const int* in_sizes, int n_in,
                              void* d_out, int out_size, void* d_ws, size_t ws_size,
                              hipStream_t stream) {
    const float* x  = (const float*)d_in[0];
    const float* wq = (const float*)d_in[1];
    const float* bq = (const float*)d_in[2];
    const float* wk = (const float*)d_in[3];
    const float* bk = (const float*)d_in[4];
    const float* wv = (const float*)d_in[5];
    const float* bv = (const float*)d_in[6];
    const float* wo = (const float*)d_in[7];
    const float* bo = (const float*)d_in[8];
    float* out = (float*)d_out;

    const int NX = BB * NN * DM;
    const int NW = 768 * 768;

    unsigned short* wsp = (unsigned short*)d_ws;
    unsigned short* xb  = wsp;
    unsigned short* wqT = xb + NX;
    unsigned short* wkT = wqT + NW;
    unsigned short* wvT = wkT + NW;
    unsigned short* woT = wvT + NW;
    unsigned short* qb  = woT + NW;
    unsigned short* kb  = qb + NX;
    unsigned short* vTb = kb + NX;
    unsigned short* zb  = vTb + NX;

    cast_x_k<<<NX / (256 * 4), 256, 0, stream>>>(x, xb, NX);
    cast_wT_k<<<dim3(144, 4), 256, 0, stream>>>(wq, wk, wv, wo, wqT, wkT, wvT, woT);
    qkv_gemm_k<<<dim3(18, 32), 256, 0, stream>>>(xb, wqT, wkT, wvT, bq, bk, bv, qb, kb, vTb);
    attn_k<<<BB * NH * (NN / 64), 256, 0, stream>>>(qb, kb, vTb, zb);
    out_gemm_k<<<dim3(6, 32), 256, 0, stream>>>(zb, woT, bo, out);
}

// Round 11
// 124.992 us; speedup vs baseline: 1.6218x; 1.0459x over previous
//
#include <hip/hip_runtime.h>
#include <hip/hip_bf16.h>
#include <math.h>

#define NH 12
#define DH 64
#define BB 2
#define NN 2048
#define DM 768

typedef short v8s __attribute__((ext_vector_type(8)));
typedef float v4f __attribute__((ext_vector_type(4)));

__device__ __forceinline__ unsigned short f2bf(float f) {
    union { float f; unsigned u; } x; x.f = f;
    unsigned r = x.u + 0x7fffu + ((x.u >> 16) & 1u);
    return (unsigned short)(r >> 16);
}

__device__ __forceinline__ int cvtpk(float lo, float hi2) {
    int r;
    asm("v_cvt_pk_bf16_f32 %0, %1, %2" : "=v"(r) : "v"(lo), "v"(hi2));
    return r;
}

__device__ __forceinline__ void glds16(const void* g, void* l) {
    __builtin_amdgcn_global_load_lds((const __attribute__((address_space(1))) void*)g,
                                     (__attribute__((address_space(3))) void*)l, 16, 0, 0);
}

// ---- cast x (fp32 -> bf16, layout-preserving) ----
__global__ __launch_bounds__(256) void cast_x_k(const float* __restrict__ in,
                                                unsigned short* __restrict__ out, int n) {
    int i = (blockIdx.x * 256 + threadIdx.x) * 4;
    if (i >= n) return;
    float4 v = *(const float4*)(in + i);
    ushort4 o;
    o.x = f2bf(v.x); o.y = f2bf(v.y); o.z = f2bf(v.z); o.w = f2bf(v.w);
    *(ushort4*)(out + i) = o;
}

// ---- cast + transpose weights via LDS tile (64x64): out[c][k] = in[k][c] ----
__global__ __launch_bounds__(256) void cast_wT_k(const float* __restrict__ w0, const float* __restrict__ w1,
                                                 const float* __restrict__ w2, const float* __restrict__ w3,
                                                 unsigned short* __restrict__ o0, unsigned short* __restrict__ o1,
                                                 unsigned short* __restrict__ o2, unsigned short* __restrict__ o3) {
    __shared__ unsigned short t[64][65];
    const float* in; unsigned short* out;
    switch (blockIdx.y) {
        case 0: in = w0; out = o0; break;
        case 1: in = w1; out = o1; break;
        case 2: in = w2; out = o2; break;
        default: in = w3; out = o3; break;
    }
    int kt = blockIdx.x / 12, ct = blockIdx.x % 12;
    int rr = threadIdx.x >> 4, cc = threadIdx.x & 15;
#pragma unroll
    for (int it = 0; it < 4; it++) {
        int row = kt * 64 + it * 16 + rr;
        int col = ct * 64 + cc * 4;
        float4 v = *(const float4*)(in + row * 768 + col);
        t[it * 16 + rr][cc * 4 + 0] = f2bf(v.x);
        t[it * 16 + rr][cc * 4 + 1] = f2bf(v.y);
        t[it * 16 + rr][cc * 4 + 2] = f2bf(v.z);
        t[it * 16 + rr][cc * 4 + 3] = f2bf(v.w);
    }
    __syncthreads();
#pragma unroll
    for (int it = 0; it < 4; it++) {
        int c_l = it * 16 + rr;
        int k_l = cc * 4;
        ushort4 o;
        o.x = t[k_l + 0][c_l];
        o.y = t[k_l + 1][c_l];
        o.z = t[k_l + 2][c_l];
        o.w = t[k_l + 3][c_l];
        *(ushort4*)(out + (ct * 64 + c_l) * 768 + kt * 64 + k_l) = o;
    }
}

// ---- fused QKV projection as one GEMM over N=2304; 3-buffer pipeline, counted vmcnt ----
__global__ __launch_bounds__(256) void qkv_gemm_k(
    const unsigned short* __restrict__ xb,
    const unsigned short* __restrict__ wqT, const unsigned short* __restrict__ wkT,
    const unsigned short* __restrict__ wvT,
    const float* __restrict__ bq, const float* __restrict__ bk, const float* __restrict__ bv,
    unsigned short* __restrict__ q, unsigned short* __restrict__ k, unsigned short* __restrict__ vT) {
    __shared__ unsigned short Abuf[3][128 * 32];
    __shared__ unsigned short Bbuf[3][128 * 32];

    int ctile = blockIdx.x;
    int mtile = blockIdx.y;
    int mat = ctile / 6;
    int col0 = (ctile % 6) * 128;
    const unsigned short* Bsrc = (mat == 0) ? wqT : ((mat == 1) ? wkT : wvT);
    const float* bias = (mat == 0) ? bq : ((mat == 1) ? bk : bv);

    int tid = threadIdx.x;
    int w = tid >> 6, l = tid & 63;
    int q16 = l & 15, g = l >> 4;
    int wr = w >> 1, wc = w & 1;

    int srow0 = tid >> 2;
    int ss = tid & 3;

    auto stage = [&](int tt, int buf) {
        int k0 = tt * 32;
#pragma unroll
        for (int i = 0; i < 2; ++i) {
            int row = srow0 + i * 64;
            int c16 = ss ^ ((row >> 1) & 3);
            glds16(xb + (mtile * 128 + row) * 768 + k0 + (c16 << 3),
                   (char*)&Abuf[buf][0] + i * 4096 + tid * 16);
            glds16(Bsrc + (col0 + row) * 768 + k0 + (c16 << 3),
                   (char*)&Bbuf[buf][0] + i * 4096 + tid * 16);
        }
    };

    v4f zero = {0.f, 0.f, 0.f, 0.f};
    v4f acc[4][4];
#pragma unroll
    for (int i = 0; i < 4; i++)
#pragma unroll
        for (int j = 0; j < 4; j++) acc[i][j] = zero;

    stage(0, 0);
    stage(1, 1);
    asm volatile("s_waitcnt vmcnt(4)" ::: "memory");
    __builtin_amdgcn_s_barrier();
    asm volatile("" ::: "memory");

    int rd = 0;
    for (int tt = 0; tt < 24; ++tt) {
        int st = rd + 2; if (st >= 3) st -= 3;
        if (tt + 2 < 24) stage(tt + 2, st);
        const char* Ab = (const char*)&Abuf[rd][0];
        const char* Bb = (const char*)&Bbuf[rd][0];
        v8s af[4], bf[4];
#pragma unroll
        for (int f = 0; f < 4; f++) {
            int arow = wr * 64 + f * 16 + q16;
            af[f] = *(const v8s*)(Ab + arow * 64 + ((g ^ ((arow >> 1) & 3)) << 4));
            int brow = wc * 64 + f * 16 + q16;
            bf[f] = *(const v8s*)(Bb + brow * 64 + ((g ^ ((brow >> 1) & 3)) << 4));
        }
#pragma unroll
        for (int i = 0; i < 4; i++)
#pragma unroll
            for (int j = 0; j < 4; j++)
                acc[i][j] = __builtin_amdgcn_mfma_f32_16x16x32_bf16(af[i], bf[j], acc[i][j], 0, 0, 0);
        asm volatile("s_waitcnt vmcnt(4)" ::: "memory");
        __builtin_amdgcn_s_barrier();
        asm volatile("" ::: "memory");
        rd = (rd + 1 == 3) ? 0 : rd + 1;
    }

    const float QSCL = 0.125f * 1.44269504088896340736f;
#pragma unroll
    for (int i = 0; i < 4; i++)
#pragma unroll
        for (int j = 0; j < 4; j++)
#pragma unroll
            for (int r = 0; r < 4; r++) {
                int gr = mtile * 128 + wr * 64 + i * 16 + 4 * g + r;
                int gcl = col0 + wc * 64 + j * 16 + q16;
                int b = gr / NN, n = gr % NN;
                int h = gcl / DH, d = gcl % DH;
                int bh = b * NH + h;
                float v = acc[i][j][r] + bias[gcl];
                if (mat == 0)      q[(bh * NN + n) * DH + d]  = f2bf(v * QSCL);
                else if (mat == 1) k[(bh * NN + n) * DH + d]  = f2bf(v);
                else               vT[(bh * DH + d) * NN + n] = f2bf(v);
            }
}

// ---- flash attention: 8 waves = 4 q-strips x 2 kv-halves; 16x16 swapped MFMA; KVBLK=32 ----
// Per wave: 16 q-rows x 1024 kv; per-score work identical to R10, per-tile halved.
// End: half-1 publishes (o,m,l) into dead K/V LDS; half-0 merges and writes z.
__global__ __launch_bounds__(512) void attn_k(
    const unsigned short* __restrict__ q, const unsigned short* __restrict__ k,
    const unsigned short* __restrict__ vT, unsigned short* __restrict__ z) {
    __shared__ __align__(16) char Kb[2][2][4096];     // [half][buf] K tile 32kv x 64d (128B rows)
    __shared__ __align__(16) char Vb[2][2][4096];     // [half][buf] V^T tile 64d x 32kv (64B rows)
    __shared__ unsigned short plds[8][16][36];        // per-wave P bounce (pad 36 -> conflict-free)

    int bh = blockIdx.x % 24;
    int qt = blockIdx.x / 24;                         // 0..31 (64 q-rows per block)
    int b = bh / NH, h = bh % NH;
    int tid = threadIdx.x;
    int w = tid >> 6, l = tid & 63;
    int q16 = l & 15, g = l >> 4;
    int ws = w & 3, hf = w >> 2;                      // q-strip, kv-half

    const unsigned short* qp = q + (size_t)bh * NN * DH;
    const unsigned short* kp = k + (size_t)bh * NN * DH;
    const unsigned short* vp = vT + (size_t)bh * DH * NN;
    int qrow = qt * 64 + ws * 16 + q16;

    v8s qf0 = *(const v8s*)(qp + qrow * DH + 8 * g);
    v8s qf1 = *(const v8s*)(qp + qrow * DH + 32 + 8 * g);

    v8s ones;
#pragma unroll
    for (int i = 0; i < 8; i++) ones[i] = (short)0x3F80;   // bf16 1.0

    // staging: 512 threads cover K (2 halves x 256 slots) and V (2 halves x 256 slots)
    int hf_s = tid >> 8;                              // staging half (uniform per wave)
    int s8 = tid & 255;
    int krow_s = s8 >> 3, ksl = s8 & 7;
    int kc16 = ksl ^ (krow_s & 7);
    int vrow_s = s8 >> 2, vsl = s8 & 3;
    int vc16 = vsl ^ (vrow_s & 3);

    auto stage = [&](int t, int buf) {
        int kv0 = hf_s * (NN / 2) + t * 32;
        glds16(kp + (kv0 + krow_s) * DH + (kc16 << 3), &Kb[hf_s][buf][s8 * 16]);
        glds16(vp + (size_t)vrow_s * NN + kv0 + (vc16 << 3), &Vb[hf_s][buf][s8 * 16]);
    };

    v4f zero = {0.f, 0.f, 0.f, 0.f};
    float mrow = -INFINITY;
    v4f o[4];
    v4f osum = zero;
#pragma unroll
    for (int dt = 0; dt < 4; dt++) o[dt] = zero;

    stage(0, 0);
    __syncthreads();

    for (int t = 0; t < 32; ++t) {
        int cur = t & 1;
        if (t + 1 < 32) stage(t + 1, cur ^ 1);

        const char* kb = &Kb[hf][cur][0];
        const char* vb = &Vb[hf][cur][0];

        // ---- QK^T: S^T[32 kv][16 q] ----
        v4f st[2];
#pragma unroll
        for (int ct = 0; ct < 2; ct++) {
            int krow = ct * 16 + q16;
            v8s kf0 = *(const v8s*)(kb + krow * 128 + ((g ^ (krow & 7)) << 4));
            v8s kf1 = *(const v8s*)(kb + krow * 128 + (((4 + g) ^ (krow & 7)) << 4));
            st[ct] = __builtin_amdgcn_mfma_f32_16x16x32_bf16(kf0, qf0, zero, 0, 0, 0);
            st[ct] = __builtin_amdgcn_mfma_f32_16x16x32_bf16(kf1, qf1, st[ct], 0, 0, 0);
        }

        // in-lane max over 8 values, then 2 shuffles across g-groups
        float ma = fmaxf(fmaxf(st[0][0], st[0][1]), st[0][2]);
        float mb = fmaxf(fmaxf(st[0][3], st[1][0]), st[1][1]);
        float vmax = fmaxf(fmaxf(ma, mb), fmaxf(st[1][2], st[1][3]));
        vmax = fmaxf(vmax, __shfl_xor(vmax, 16));
        vmax = fmaxf(vmax, __shfl_xor(vmax, 32));

        // defer-max (THR=8, log2 domain)
        if (!__all(vmax <= mrow + 8.f)) {
            float mn = fmaxf(mrow, vmax);
            float sc = exp2f(mrow - mn);
#pragma unroll
            for (int dt = 0; dt < 4; dt++)
#pragma unroll
                for (int r = 0; r < 4; r++) o[dt][r] *= sc;
            osum[0] *= sc;
            mrow = mn;
        }

        // exp + pack (cvt_pk) + P bounce through padded LDS
#pragma unroll
        for (int ct = 0; ct < 2; ct++) {
            float p0 = exp2f(st[ct][0] - mrow);
            float p1 = exp2f(st[ct][1] - mrow);
            float p2 = exp2f(st[ct][2] - mrow);
            float p3 = exp2f(st[ct][3] - mrow);
            union { int i[2]; short4 s; } u;
            u.i[0] = cvtpk(p0, p1);
            u.i[1] = cvtpk(p2, p3);
            *(short4*)(&plds[w][q16][ct * 16 + 4 * g]) = u.s;
        }

        v8s pf0 = *(const v8s*)(&plds[w][q16][8 * g]);

        // lsum via ones-MFMA
        osum = __builtin_amdgcn_mfma_f32_16x16x32_bf16(ones, pf0, osum, 0, 0, 0);

        // ---- PV: O^T[16 d][16 q] per dt ----
#pragma unroll
        for (int dt = 0; dt < 4; dt++) {
            int dcol = dt * 16 + q16;
            v8s vf = *(const v8s*)(vb + dcol * 64 + ((g ^ (dcol & 3)) << 4));
            o[dt] = __builtin_amdgcn_mfma_f32_16x16x32_bf16(vf, pf0, o[dt], 0, 0, 0);
        }
        __syncthreads();
    }

    // ---- cross-half merge via LDS (K/V buffers are dead now) ----
    float* po = (float*)&Kb[0][0][0];     // 64 rows x 64 d f32 = 16 KB
    float* pm = (float*)&Vb[0][0][0];     // pm[64], pl[64]
    float* pl = pm + 64;
    int row = ws * 16 + q16;

    if (hf == 1) {
#pragma unroll
        for (int dt = 0; dt < 4; dt++)
#pragma unroll
            for (int r = 0; r < 4; r++)
                po[row * 64 + dt * 16 + 4 * g + r] = o[dt][r];
        if (g == 0) { pm[row] = mrow; pl[row] = osum[0]; }
    }
    __syncthreads();
    if (hf == 0) {
        float m1 = pm[row], l1 = pl[row];
        float ms = fmaxf(mrow, m1);
        float a0 = exp2f(mrow - ms), a1 = exp2f(m1 - ms);
        float inv = 1.f / (osum[0] * a0 + l1 * a1);
        int n = qt * 64 + ws * 16 + q16;
#pragma unroll
        for (int dt = 0; dt < 4; dt++) {
            short4 s4;
            s4.x = (short)f2bf((o[dt][0] * a0 + po[row * 64 + dt * 16 + 4 * g + 0] * a1) * inv);
            s4.y = (short)f2bf((o[dt][1] * a0 + po[row * 64 + dt * 16 + 4 * g + 1] * a1) * inv);
            s4.z = (short)f2bf((o[dt][2] * a0 + po[row * 64 + dt * 16 + 4 * g + 2] * a1) * inv);
            s4.w = (short)f2bf((o[dt][3] * a0 + po[row * 64 + dt * 16 + 4 * g + 3] * a1) * inv);
            *(short4*)(&z[((size_t)(b * NN + n)) * DM + h * DH + dt * 16 + 4 * g]) = s4;
        }
    }
}

// ---- output projection: z[4096,768] @ wo + bo -> fp32; 3-buffer pipeline ----
__global__ __launch_bounds__(256) void out_gemm_k(
    const unsigned short* __restrict__ zb, const unsigned short* __restrict__ woT,
    const float* __restrict__ bo, float* __restrict__ out) {
    __shared__ unsigned short Abuf[3][128 * 32];
    __shared__ unsigned short Bbuf[3][128 * 32];

    int ctile = blockIdx.x;
    int mtile = blockIdx.y;
    int col0 = ctile * 128;

    int tid = threadIdx.x;
    int w = tid >> 6, l = tid & 63;
    int q16 = l & 15, g = l >> 4;
    int wr = w >> 1, wc = w & 1;

    int srow0 = tid >> 2;
    int ss = tid & 3;

    auto stage = [&](int tt, int buf) {
        int k0 = tt * 32;
#pragma unroll
        for (int i = 0; i < 2; ++i) {
            int row = srow0 + i * 64;
            int c16 = ss ^ ((row >> 1) & 3);
            glds16(zb + (mtile * 128 + row) * 768 + k0 + (c16 << 3),
                   (char*)&Abuf[buf][0] + i * 4096 + tid * 16);
            glds16(woT + (col0 + row) * 768 + k0 + (c16 << 3),
                   (char*)&Bbuf[buf][0] + i * 4096 + tid * 16);
        }
    };

    v4f zero = {0.f, 0.f, 0.f, 0.f};
    v4f acc[4][4];
#pragma unroll
    for (int i = 0; i < 4; i++)
#pragma unroll
        for (int j = 0; j < 4; j++) acc[i][j] = zero;

    stage(0, 0);
    stage(1, 1);
    asm volatile("s_waitcnt vmcnt(4)" ::: "memory");
    __builtin_amdgcn_s_barrier();
    asm volatile("" ::: "memory");

    int rd = 0;
    for (int tt = 0; tt < 24; ++tt) {
        int st = rd + 2; if (st >= 3) st -= 3;
        if (tt + 2 < 24) stage(tt + 2, st);
        const char* Ab = (const char*)&Abuf[rd][0];
        const char* Bb = (const char*)&Bbuf[rd][0];
        v8s af[4], bf[4];
#pragma unroll
        for (int f = 0; f < 4; f++) {
            int arow = wr * 64 + f * 16 + q16;
            af[f] = *(const v8s*)(Ab + arow * 64 + ((g ^ ((arow >> 1) & 3)) << 4));
            int brow = wc * 64 + f * 16 + q16;
            bf[f] = *(const v8s*)(Bb + brow * 64 + ((g ^ ((brow >> 1) & 3)) << 4));
        }
#pragma unroll
        for (int i = 0; i < 4; i++)
#pragma unroll
            for (int j = 0; j < 4; j++)
                acc[i][j] = __builtin_amdgcn_mfma_f32_16x16x32_bf16(af[i], bf[j], acc[i][j], 0, 0, 0);
        asm volatile("s_waitcnt vmcnt(4)" ::: "memory");
        __builtin_amdgcn_s_barrier();
        asm volatile("" ::: "memory");
        rd = (rd + 1 == 3) ? 0 : rd + 1;
    }

#pragma unroll
    for (int i = 0; i < 4; i++)
#pragma unroll
        for (int j = 0; j < 4; j++)
#pragma unroll
            for (int r = 0; r < 4; r++) {
                int gr = mtile * 128 + wr * 64 + i * 16 + 4 * g + r;
                int gc = col0 + wc * 64 + j * 16 + q16;
                out[gr * 768 + gc] = acc[i][j][r] + bo[gc];
            }
}

extern "C" void kernel_launch(void* const* d_in, const int* in_sizes, int n_in,
                              void* d_out, int out_size, void* d_ws, size_t ws_size,
                              hipStream_t stream) {
    const float* x  = (const float*)d_in[0];
    const float* wq = (const float*)d_in[1];
    const float* bq = (const float*)d_in[2];
    const float* wk = (const float*)d_in[3];
    const float* bk = (const float*)d_in[4];
    const float* wv = (const float*)d_in[5];
    const float* bv = (const float*)d_in[6];
    const float* wo = (const float*)d_in[7];
    const float* bo = (const float*)d_in[8];
    float* out = (float*)d_out;

    const int NX = BB * NN * DM;
    const int NW = 768 * 768;

    unsigned short* wsp = (unsigned short*)d_ws;
    unsigned short* xb  = wsp;
    unsigned short* wqT = xb + NX;
    unsigned short* wkT = wqT + NW;
    unsigned short* wvT = wkT + NW;
    unsigned short* woT = wvT + NW;
    unsigned short* qb  = woT + NW;
    unsigned short* kb  = qb + NX;
    unsigned short* vTb = kb + NX;
    unsigned short* zb  = vTb + NX;

    cast_x_k<<<NX / (256 * 4), 256, 0, stream>>>(x, xb, NX);
    cast_wT_k<<<dim3(144, 4), 256, 0, stream>>>(wq, wk, wv, wo, wqT, wkT, wvT, woT);
    qkv_gemm_k<<<dim3(18, 32), 256, 0, stream>>>(xb, wqT, wkT, wvT, bq, bk, bv, qb, kb, vTb);
    attn_k<<<BB * NH * (NN / 64), 512, 0, stream>>>(qb, kb, vTb, zb);
    out_gemm_k<<<dim3(6, 32), 256, 0, stream>>>(zb, woT, bo, out);
}

// Round 12
// 119.271 us; speedup vs baseline: 1.6995x; 1.0480x over previous
//
#include <hip/hip_runtime.h>
#include <hip/hip_bf16.h>
#include <math.h>

#define NH 12
#define DH 64
#define BB 2
#define NN 2048
#define DM 768

typedef short v8s __attribute__((ext_vector_type(8)));
typedef float v4f __attribute__((ext_vector_type(4)));

__device__ __forceinline__ unsigned short f2bf(float f) {
    union { float f; unsigned u; } x; x.f = f;
    unsigned r = x.u + 0x7fffu + ((x.u >> 16) & 1u);
    return (unsigned short)(r >> 16);
}

__device__ __forceinline__ int cvtpk(float lo, float hi2) {
    int r;
    asm("v_cvt_pk_bf16_f32 %0, %1, %2" : "=v"(r) : "v"(lo), "v"(hi2));
    return r;
}

__device__ __forceinline__ void glds16(const void* g, void* l) {
    __builtin_amdgcn_global_load_lds((const __attribute__((address_space(1))) void*)g,
                                     (__attribute__((address_space(3))) void*)l, 16, 0, 0);
}

// ---- cast x (fp32 -> bf16, layout-preserving) ----
__global__ __launch_bounds__(256) void cast_x_k(const float* __restrict__ in,
                                                unsigned short* __restrict__ out, int n) {
    int i = (blockIdx.x * 256 + threadIdx.x) * 4;
    if (i >= n) return;
    float4 v = *(const float4*)(in + i);
    ushort4 o;
    o.x = f2bf(v.x); o.y = f2bf(v.y); o.z = f2bf(v.z); o.w = f2bf(v.w);
    *(ushort4*)(out + i) = o;
}

// ---- cast + transpose weights via LDS tile (64x64): out[c][k] = in[k][c] ----
__global__ __launch_bounds__(256) void cast_wT_k(const float* __restrict__ w0, const float* __restrict__ w1,
                                                 const float* __restrict__ w2, const float* __restrict__ w3,
                                                 unsigned short* __restrict__ o0, unsigned short* __restrict__ o1,
                                                 unsigned short* __restrict__ o2, unsigned short* __restrict__ o3) {
    __shared__ unsigned short t[64][65];
    const float* in; unsigned short* out;
    switch (blockIdx.y) {
        case 0: in = w0; out = o0; break;
        case 1: in = w1; out = o1; break;
        case 2: in = w2; out = o2; break;
        default: in = w3; out = o3; break;
    }
    int kt = blockIdx.x / 12, ct = blockIdx.x % 12;
    int rr = threadIdx.x >> 4, cc = threadIdx.x & 15;
#pragma unroll
    for (int it = 0; it < 4; it++) {
        int row = kt * 64 + it * 16 + rr;
        int col = ct * 64 + cc * 4;
        float4 v = *(const float4*)(in + row * 768 + col);
        t[it * 16 + rr][cc * 4 + 0] = f2bf(v.x);
        t[it * 16 + rr][cc * 4 + 1] = f2bf(v.y);
        t[it * 16 + rr][cc * 4 + 2] = f2bf(v.z);
        t[it * 16 + rr][cc * 4 + 3] = f2bf(v.w);
    }
    __syncthreads();
#pragma unroll
    for (int it = 0; it < 4; it++) {
        int c_l = it * 16 + rr;
        int k_l = cc * 4;
        ushort4 o;
        o.x = t[k_l + 0][c_l];
        o.y = t[k_l + 1][c_l];
        o.z = t[k_l + 2][c_l];
        o.w = t[k_l + 3][c_l];
        *(ushort4*)(out + (ct * 64 + c_l) * 768 + kt * 64 + k_l) = o;
    }
}

// ---- fused QKV projection as one GEMM over N=2304; 8 waves, wave tile 64x32 ----
__global__ __launch_bounds__(512) void qkv_gemm_k(
    const unsigned short* __restrict__ xb,
    const unsigned short* __restrict__ wqT, const unsigned short* __restrict__ wkT,
    const unsigned short* __restrict__ wvT,
    const float* __restrict__ bq, const float* __restrict__ bk, const float* __restrict__ bv,
    unsigned short* __restrict__ q, unsigned short* __restrict__ k, unsigned short* __restrict__ vT) {
    __shared__ unsigned short Abuf[3][128 * 32];
    __shared__ unsigned short Bbuf[3][128 * 32];

    int ctile = blockIdx.x;
    int mtile = blockIdx.y;
    int mat = ctile / 6;
    int col0 = (ctile % 6) * 128;
    const unsigned short* Bsrc = (mat == 0) ? wqT : ((mat == 1) ? wkT : wvT);
    const float* bias = (mat == 0) ? bq : ((mat == 1) ? bk : bv);

    int tid = threadIdx.x;
    int w = tid >> 6, l = tid & 63;
    int q16 = l & 15, g = l >> 4;
    int wr = w >> 2, wc = w & 3;         // wave tile: rows wr*64, cols wc*32

    int srow = tid >> 2;                 // 0..127
    int ss = tid & 3;
    int c16s = ss ^ ((srow >> 1) & 3);

    auto stage = [&](int tt, int buf) {
        int k0 = tt * 32;
        glds16(xb + (mtile * 128 + srow) * 768 + k0 + (c16s << 3),
               (char*)&Abuf[buf][0] + tid * 16);
        glds16(Bsrc + (col0 + srow) * 768 + k0 + (c16s << 3),
               (char*)&Bbuf[buf][0] + tid * 16);
    };

    v4f zero = {0.f, 0.f, 0.f, 0.f};
    v4f acc[4][2];
#pragma unroll
    for (int i = 0; i < 4; i++)
#pragma unroll
        for (int j = 0; j < 2; j++) acc[i][j] = zero;

    stage(0, 0);
    stage(1, 1);
    asm volatile("s_waitcnt vmcnt(2)" ::: "memory");
    __builtin_amdgcn_s_barrier();
    asm volatile("" ::: "memory");

    int rd = 0;
    for (int tt = 0; tt < 24; ++tt) {
        int st = rd + 2; if (st >= 3) st -= 3;
        if (tt + 2 < 24) stage(tt + 2, st);
        const char* Ab = (const char*)&Abuf[rd][0];
        const char* Bb = (const char*)&Bbuf[rd][0];
        v8s af[4], bf[2];
#pragma unroll
        for (int f = 0; f < 4; f++) {
            int arow = wr * 64 + f * 16 + q16;
            af[f] = *(const v8s*)(Ab + arow * 64 + ((g ^ ((arow >> 1) & 3)) << 4));
        }
#pragma unroll
        for (int j = 0; j < 2; j++) {
            int brow = wc * 32 + j * 16 + q16;
            bf[j] = *(const v8s*)(Bb + brow * 64 + ((g ^ ((brow >> 1) & 3)) << 4));
        }
#pragma unroll
        for (int i = 0; i < 4; i++)
#pragma unroll
            for (int j = 0; j < 2; j++)
                acc[i][j] = __builtin_amdgcn_mfma_f32_16x16x32_bf16(af[i], bf[j], acc[i][j], 0, 0, 0);
        asm volatile("s_waitcnt vmcnt(2)" ::: "memory");
        __builtin_amdgcn_s_barrier();
        asm volatile("" ::: "memory");
        rd = (rd + 1 == 3) ? 0 : rd + 1;
    }

    const float QSCL = 0.125f * 1.44269504088896340736f;
#pragma unroll
    for (int i = 0; i < 4; i++)
#pragma unroll
        for (int j = 0; j < 2; j++)
#pragma unroll
            for (int r = 0; r < 4; r++) {
                int gr = mtile * 128 + wr * 64 + i * 16 + 4 * g + r;
                int gcl = col0 + wc * 32 + j * 16 + q16;
                int b = gr / NN, n = gr % NN;
                int h = gcl / DH, d = gcl % DH;
                int bh = b * NH + h;
                float v = acc[i][j][r] + bias[gcl];
                if (mat == 0)      q[(bh * NN + n) * DH + d]  = f2bf(v * QSCL);
                else if (mat == 1) k[(bh * NN + n) * DH + d]  = f2bf(v);
                else               vT[(bh * DH + d) * NN + n] = f2bf(v);
            }
}

// ---- flash attention: 8 waves = 4 q-strips x 2 kv-halves; KVBLK=32 ----
// V tile re-laid to 128B rows: row r = { V^T[r][kv 0..32) | V^T[r+32][kv 0..32) },
// 8-slot swizzle s = j ^ (r&7) -> PV ds_read_b128 spreads over all 8 bank-groups.
__global__ __launch_bounds__(512) void attn_k(
    const unsigned short* __restrict__ q, const unsigned short* __restrict__ k,
    const unsigned short* __restrict__ vT, unsigned short* __restrict__ z) {
    __shared__ __align__(16) char Kb[2][2][4096];     // [half][buf] K tile 32kv x 64d (128B rows)
    __shared__ __align__(16) char Vb[2][2][4096];     // [half][buf] V tile 32 rows x 128B (paired d)
    __shared__ unsigned short plds[8][16][36];

    int bh = blockIdx.x % 24;
    int qt = blockIdx.x / 24;
    int b = bh / NH, h = bh % NH;
    int tid = threadIdx.x;
    int w = tid >> 6, l = tid & 63;
    int q16 = l & 15, g = l >> 4;
    int ws = w & 3, hf = w >> 2;

    const unsigned short* qp = q + (size_t)bh * NN * DH;
    const unsigned short* kp = k + (size_t)bh * NN * DH;
    const unsigned short* vp = vT + (size_t)bh * DH * NN;
    int qrow = qt * 64 + ws * 16 + q16;

    v8s qf0 = *(const v8s*)(qp + qrow * DH + 8 * g);
    v8s qf1 = *(const v8s*)(qp + qrow * DH + 32 + 8 * g);

    v8s ones;
#pragma unroll
    for (int i = 0; i < 8; i++) ones[i] = (short)0x3F80;   // bf16 1.0

    // staging: 512 threads cover K (2 halves x 256 slots) and V (2 halves x 256 slots)
    int hf_s = tid >> 8;
    int s8 = tid & 255;
    int row_s = s8 >> 3, sl = s8 & 7;
    int kc16 = (sl ^ (row_s & 7)) & 7;                // K row is 8 slots of 16B
    // V: logical slot j = sl ^ (row&7); d = row + (j>>2)*32; kv word = j&3
    int vj = sl ^ (row_s & 7);
    int vd = row_s + ((vj >> 2) << 5);
    int vkw = vj & 3;

    auto stage = [&](int t, int buf) {
        int kv0 = hf_s * (NN / 2) + t * 32;
        // K rows are 64 d-elems = 128B = 8 slots; but K tile is 32 rows -> row_s>=32 maps to rows 0..31 twice?
        // K tile: 32 kv rows x 128B = 256 slots: row = s8>>3 in 0..31. OK.
        glds16(kp + (kv0 + row_s) * DH + (kc16 << 3), &Kb[hf_s][buf][s8 * 16]);
        glds16(vp + (size_t)vd * NN + kv0 + vkw * 8, &Vb[hf_s][buf][s8 * 16]);
    };

    v4f zero = {0.f, 0.f, 0.f, 0.f};
    float mrow = -INFINITY;
    v4f o[4];
    v4f osum = zero;
#pragma unroll
    for (int dt = 0; dt < 4; dt++) o[dt] = zero;

    stage(0, 0);
    __syncthreads();

    for (int t = 0; t < 32; ++t) {
        int cur = t & 1;
        if (t + 1 < 32) stage(t + 1, cur ^ 1);

        const char* kb = &Kb[hf][cur][0];
        const char* vb = &Vb[hf][cur][0];

        // ---- QK^T: S^T[32 kv][16 q] ----
        v4f st[2];
#pragma unroll
        for (int ct = 0; ct < 2; ct++) {
            int krow = ct * 16 + q16;
            v8s kf0 = *(const v8s*)(kb + krow * 128 + ((g ^ (krow & 7)) << 4));
            v8s kf1 = *(const v8s*)(kb + krow * 128 + (((4 + g) ^ (krow & 7)) << 4));
            st[ct] = __builtin_amdgcn_mfma_f32_16x16x32_bf16(kf0, qf0, zero, 0, 0, 0);
            st[ct] = __builtin_amdgcn_mfma_f32_16x16x32_bf16(kf1, qf1, st[ct], 0, 0, 0);
        }

        float ma = fmaxf(fmaxf(st[0][0], st[0][1]), st[0][2]);
        float mb = fmaxf(fmaxf(st[0][3], st[1][0]), st[1][1]);
        float vmax = fmaxf(fmaxf(ma, mb), fmaxf(st[1][2], st[1][3]));
        vmax = fmaxf(vmax, __shfl_xor(vmax, 16));
        vmax = fmaxf(vmax, __shfl_xor(vmax, 32));

        if (!__all(vmax <= mrow + 8.f)) {
            float mn = fmaxf(mrow, vmax);
            float sc = exp2f(mrow - mn);
#pragma unroll
            for (int dt = 0; dt < 4; dt++)
#pragma unroll
                for (int r = 0; r < 4; r++) o[dt][r] *= sc;
            osum[0] *= sc;
            mrow = mn;
        }

#pragma unroll
        for (int ct = 0; ct < 2; ct++) {
            float p0 = exp2f(st[ct][0] - mrow);
            float p1 = exp2f(st[ct][1] - mrow);
            float p2 = exp2f(st[ct][2] - mrow);
            float p3 = exp2f(st[ct][3] - mrow);
            union { int i[2]; short4 s; } u;
            u.i[0] = cvtpk(p0, p1);
            u.i[1] = cvtpk(p2, p3);
            *(short4*)(&plds[w][q16][ct * 16 + 4 * g]) = u.s;
        }

        v8s pf0 = *(const v8s*)(&plds[w][q16][8 * g]);

        osum = __builtin_amdgcn_mfma_f32_16x16x32_bf16(ones, pf0, osum, 0, 0, 0);

        // ---- PV: O^T[16 d][16 q] per dt; V row = dcol&31, slot = ((dcol>>5)*4+g)^(row&7) ----
#pragma unroll
        for (int dt = 0; dt < 4; dt++) {
            int dcol = dt * 16 + q16;
            int rr = dcol & 31;
            int sl2 = (((dcol >> 5) << 2) + g) ^ (rr & 7);
            v8s vf = *(const v8s*)(vb + rr * 128 + (sl2 << 4));
            o[dt] = __builtin_amdgcn_mfma_f32_16x16x32_bf16(vf, pf0, o[dt], 0, 0, 0);
        }
        __syncthreads();
    }

    // ---- cross-half merge via LDS (K/V buffers dead) ----
    float* po = (float*)&Kb[0][0][0];
    float* pm = (float*)&Vb[0][0][0];
    float* pl = pm + 64;
    int row = ws * 16 + q16;

    if (hf == 1) {
#pragma unroll
        for (int dt = 0; dt < 4; dt++)
#pragma unroll
            for (int r = 0; r < 4; r++)
                po[row * 64 + dt * 16 + 4 * g + r] = o[dt][r];
        if (g == 0) { pm[row] = mrow; pl[row] = osum[0]; }
    }
    __syncthreads();
    if (hf == 0) {
        float m1 = pm[row], l1 = pl[row];
        float ms = fmaxf(mrow, m1);
        float a0 = exp2f(mrow - ms), a1 = exp2f(m1 - ms);
        float inv = 1.f / (osum[0] * a0 + l1 * a1);
        int n = qt * 64 + ws * 16 + q16;
#pragma unroll
        for (int dt = 0; dt < 4; dt++) {
            short4 s4;
            s4.x = (short)f2bf((o[dt][0] * a0 + po[row * 64 + dt * 16 + 4 * g + 0] * a1) * inv);
            s4.y = (short)f2bf((o[dt][1] * a0 + po[row * 64 + dt * 16 + 4 * g + 1] * a1) * inv);
            s4.z = (short)f2bf((o[dt][2] * a0 + po[row * 64 + dt * 16 + 4 * g + 2] * a1) * inv);
            s4.w = (short)f2bf((o[dt][3] * a0 + po[row * 64 + dt * 16 + 4 * g + 3] * a1) * inv);
            *(short4*)(&z[((size_t)(b * NN + n)) * DM + h * DH + dt * 16 + 4 * g]) = s4;
        }
    }
}

// ---- output projection: z[4096,768] @ wo + bo -> fp32; 8 waves, wave tile 64x32 ----
__global__ __launch_bounds__(512) void out_gemm_k(
    const unsigned short* __restrict__ zb, const unsigned short* __restrict__ woT,
    const float* __restrict__ bo, float* __restrict__ out) {
    __shared__ unsigned short Abuf[3][128 * 32];
    __shared__ unsigned short Bbuf[3][128 * 32];

    int ctile = blockIdx.x;
    int mtile = blockIdx.y;
    int col0 = ctile * 128;

    int tid = threadIdx.x;
    int w = tid >> 6, l = tid & 63;
    int q16 = l & 15, g = l >> 4;
    int wr = w >> 2, wc = w & 3;

    int srow = tid >> 2;
    int ss = tid & 3;
    int c16s = ss ^ ((srow >> 1) & 3);

    auto stage = [&](int tt, int buf) {
        int k0 = tt * 32;
        glds16(zb + (mtile * 128 + srow) * 768 + k0 + (c16s << 3),
               (char*)&Abuf[buf][0] + tid * 16);
        glds16(woT + (col0 + srow) * 768 + k0 + (c16s << 3),
               (char*)&Bbuf[buf][0] + tid * 16);
    };

    v4f zero = {0.f, 0.f, 0.f, 0.f};
    v4f acc[4][2];
#pragma unroll
    for (int i = 0; i < 4; i++)
#pragma unroll
        for (int j = 0; j < 2; j++) acc[i][j] = zero;

    stage(0, 0);
    stage(1, 1);
    asm volatile("s_waitcnt vmcnt(2)" ::: "memory");
    __builtin_amdgcn_s_barrier();
    asm volatile("" ::: "memory");

    int rd = 0;
    for (int tt = 0; tt < 24; ++tt) {
        int st = rd + 2; if (st >= 3) st -= 3;
        if (tt + 2 < 24) stage(tt + 2, st);
        const char* Ab = (const char*)&Abuf[rd][0];
        const char* Bb = (const char*)&Bbuf[rd][0];
        v8s af[4], bf[2];
#pragma unroll
        for (int f = 0; f < 4; f++) {
            int arow = wr * 64 + f * 16 + q16;
            af[f] = *(const v8s*)(Ab + arow * 64 + ((g ^ ((arow >> 1) & 3)) << 4));
        }
#pragma unroll
        for (int j = 0; j < 2; j++) {
            int brow = wc * 32 + j * 16 + q16;
            bf[j] = *(const v8s*)(Bb + brow * 64 + ((g ^ ((brow >> 1) & 3)) << 4));
        }
#pragma unroll
        for (int i = 0; i < 4; i++)
#pragma unroll
            for (int j = 0; j < 2; j++)
                acc[i][j] = __builtin_amdgcn_mfma_f32_16x16x32_bf16(af[i], bf[j], acc[i][j], 0, 0, 0);
        asm volatile("s_waitcnt vmcnt(2)" ::: "memory");
        __builtin_amdgcn_s_barrier();
        asm volatile("" ::: "memory");
        rd = (rd + 1 == 3) ? 0 : rd + 1;
    }

#pragma unroll
    for (int i = 0; i < 4; i++)
#pragma unroll
        for (int j = 0; j < 2; j++)
#pragma unroll
            for (int r = 0; r < 4; r++) {
                int gr = mtile * 128 + wr * 64 + i * 16 + 4 * g + r;
                int gc = col0 + wc * 32 + j * 16 + q16;
                out[gr * 768 + gc] = acc[i][j][r] + bo[gc];
            }
}

extern "C" void kernel_launch(void* const* d_in, const int* in_sizes, int n_in,
                              void* d_out, int out_size, void* d_ws, size_t ws_size,
                              hipStream_t stream) {
    const float* x  = (const float*)d_in[0];
    const float* wq = (const float*)d_in[1];
    const float* bq = (const float*)d_in[2];
    const float* wk = (const float*)d_in[3];
    const float* bk = (const float*)d_in[4];
    const float* wv = (const float*)d_in[5];
    const float* bv = (const float*)d_in[6];
    const float* wo = (const float*)d_in[7];
    const float* bo = (const float*)d_in[8];
    float* out = (float*)d_out;

    const int NX = BB * NN * DM;
    const int NW = 768 * 768;

    unsigned short* wsp = (unsigned short*)d_ws;
    unsigned short* xb  = wsp;
    unsigned short* wqT = xb + NX;
    unsigned short* wkT = wqT + NW;
    unsigned short* wvT = wkT + NW;
    unsigned short* woT = wvT + NW;
    unsigned short* qb  = woT + NW;
    unsigned short* kb  = qb + NX;
    unsigned short* vTb = kb + NX;
    unsigned short* zb  = vTb + NX;

    cast_x_k<<<NX / (256 * 4), 256, 0, stream>>>(x, xb, NX);
    cast_wT_k<<<dim3(144, 4), 256, 0, stream>>>(wq, wk, wv, wo, wqT, wkT, wvT, woT);
    qkv_gemm_k<<<dim3(18, 32), 512, 0, stream>>>(xb, wqT, wkT, wvT, bq, bk, bv, qb, kb, vTb);
    attn_k<<<BB * NH * (NN / 64), 512, 0, stream>>>(qb, kb, vTb, zb);
    out_gemm_k<<<dim3(6, 32), 512, 0, stream>>>(zb, woT, bo, out);
}